// Round 13
// baseline (855.472 us; speedup 1.0000x reference)
//
#include <hip/hip_runtime.h>
#include <hip/hip_bf16.h>
#include <math.h>

#define N_NODES 1024
#define T_STEPS 32
#define F_DIM   128
#define H_HEADS 4
#define D_HEAD  32
#define DEG     32
#define HID     512
#define OUT_DIM 64
#define TF      (T_STEPS * F_DIM)   // 4096
#define NT      (N_NODES * T_STEPS) // 32768
#define F3      (3 * F_DIM)         // 384

typedef __attribute__((ext_vector_type(8))) __bf16 bf16x8;
typedef __attribute__((ext_vector_type(4))) float  f32x4;
typedef __attribute__((ext_vector_type(8))) unsigned short ush8;

// float -> bf16 bits, round-to-nearest-even (scalar fallback)
__device__ __forceinline__ short f2bf(float x) {
    union { float f; unsigned u; } v; v.f = x;
    unsigned r = (v.u + 0x7FFFu + ((v.u >> 16) & 1u)) >> 16;
    return (short)r;
}
__device__ __forceinline__ float bf2f(unsigned short b) {
    union { unsigned u; float f; } v; v.u = ((unsigned)b) << 16; return v.f;
}

// ---------------------------------------------------------------- utilities
// one-time: Whh_bf = bf16(W_hh) [384,128] (rows ARE the GH weight columns);
// WgT_bf[f][k] = bf16(W_gcn[k][f]) (per-thread-contiguous GCN columns)
__global__ void prep_weights(const float* __restrict__ W_hh, const float* __restrict__ W_gcn,
                             unsigned short* __restrict__ Whh_bf,
                             unsigned short* __restrict__ WgT_bf) {
    int idx = blockIdx.x * 256 + threadIdx.x;
    if (idx < F3 * F_DIM) {
        Whh_bf[idx] = (unsigned short)f2bf(W_hh[idx]);
    }
    if (idx < F_DIM * F_DIM) {
        int k = idx >> 7, f = idx & 127;
        WgT_bf[f * 128 + k] = (unsigned short)f2bf(W_gcn[idx]);
    }
}

// split-K partial reduction + bias (+relu)
template <bool RELU>
__global__ void reduce_bias(const float* __restrict__ part, int nz, int MP,
                            const float* __restrict__ bias, int P,
                            float* __restrict__ C) {
    int i = blockIdx.x * 256 + threadIdx.x;
    if (i < MP) {
        float v = bias[i & (P - 1)];
        for (int z = 0; z < nz; ++z) v += part[(size_t)z * MP + i];
        if (RELU) v = fmaxf(v, 0.f);
        C[i] = v;
    }
}

// ---------------------------------------------------------------- SpMM (wide): Y[n, :] = sum_e vals * X[cols[e], :]
__global__ void spmm_wide(const int* __restrict__ cols, const float* __restrict__ vals,
                          const float* __restrict__ X, short* __restrict__ Y) {
    int n = blockIdx.x;
    int c = blockIdx.y * 256 + threadIdx.x;
    const int*   ce = cols + n * DEG;
    const float* ve = vals + n * DEG;
    float acc = 0.f;
#pragma unroll
    for (int e = 0; e < DEG; ++e) acc += ve[e] * X[(size_t)ce[e] * TF + c];
    Y[(size_t)n * TF + c] = f2bf(acc);
}

// ---------------------------------------------------------------- t=0 gates: h=0, GH=0 algebraically; pe(t=0)=sin(0)=0
__global__ __launch_bounds__(256) void gates0_kernel(
        const float* __restrict__ GI, const float* __restrict__ b_hh,
        float* __restrict__ g_out, float* __restrict__ Hm) {
    int idx = blockIdx.x * 256 + threadIdx.x;   // over N*F
    int n = idx >> 7, f = idx & 127;
    size_t gib = (size_t)n * T_STEPS * F3;
    float rr = 1.f / (1.f + expf(-(GI[gib + f] + b_hh[f])));
    float zz = 1.f / (1.f + expf(-(GI[gib + 128 + f] + b_hh[128 + f])));
    float nn = tanhf(GI[gib + 256 + f] + rr * b_hh[256 + f]);
    float g  = (1.f - zz) * nn;
    g_out[idx] = g;
    Hm[(size_t)n * T_STEPS * F_DIM + f] = g;    // pe = 0 at t=0
}

// ---------------------------------------------------------------- fully fused scan step, 2 nodes/block (512 blocks)
// Weights now read as contiguous b128 runs per thread (32 loads/thread/step).
__global__ __launch_bounds__(256) void scan_step(
        const int* __restrict__ cols, const float* __restrict__ vals,
        const float* __restrict__ g_in, const unsigned short* __restrict__ WgT_bf,
        const unsigned short* __restrict__ Whh_bf, const float* __restrict__ b_hh,
        const float* __restrict__ GI, float* __restrict__ g_out,
        float* __restrict__ Hm, int t_next) {
    __shared__ float sp[2][F_DIM];
    __shared__ float hsn[2][F_DIM];
    __shared__ float part[2][F_DIM][8];    // 6 used, +2 pad
    __shared__ float gpart[2][2][F_DIM];
    int tid = threadIdx.x;
    int n0 = blockIdx.x * 2;
    int f = tid & 127, half = tid >> 7;
    // ---- SpMM: edges split across halves
    float b0 = 0.f, b1 = 0.f;
    int eb = half * 16;
#pragma unroll
    for (int e = 0; e < 16; ++e) {
        int i0 = n0 * DEG + eb + e;
        int i1 = (n0 + 1) * DEG + eb + e;
        b0 += vals[i0] * g_in[cols[i0] * F_DIM + f];
        b1 += vals[i1] * g_in[cols[i1] * F_DIM + f];
    }
    gpart[half][0][f] = b0; gpart[half][1][f] = b1;
    __syncthreads();
    sp[half][f] = gpart[0][half][f] + gpart[1][half][f];   // half doubles as node idx
    __syncthreads();
    // ---- GCN: k range split across halves; contiguous bf16 weight runs
    int kb = half * 64;
    float c0 = 0.f, c1 = 0.f;
    {
        const unsigned short* wgp = WgT_bf + f * 128 + kb;
#pragma unroll
        for (int i = 0; i < 8; ++i) {
            ush8 wv = *(const ush8*)(wgp + i * 8);
#pragma unroll
            for (int j = 0; j < 8; ++j) {
                int kk = kb + i * 8 + j;
                float w = bf2f(wv[j]);
                c0 += sp[0][kk] * w; c1 += sp[1][kk] * w;
            }
        }
    }
    gpart[half][0][f] = c0; gpart[half][1][f] = c1;
    __syncthreads();
    hsn[half][f] = fmaxf(gpart[0][half][f] + gpart[1][half][f], 0.f);
    __syncthreads();
    // ---- GH = h_new @ W_hh^T : k split; W_hh rows are the needed columns
    float a[6] = {0.f, 0.f, 0.f, 0.f, 0.f, 0.f};
    {
        const unsigned short* w0p = Whh_bf + (size_t)(f)       * 128 + kb;
        const unsigned short* w1p = Whh_bf + (size_t)(128 + f) * 128 + kb;
        const unsigned short* w2p = Whh_bf + (size_t)(256 + f) * 128 + kb;
#pragma unroll
        for (int i = 0; i < 8; ++i) {
            ush8 wr8 = *(const ush8*)(w0p + i * 8);
            ush8 wz8 = *(const ush8*)(w1p + i * 8);
            ush8 wn8 = *(const ush8*)(w2p + i * 8);
#pragma unroll
            for (int j = 0; j < 8; ++j) {
                int kk = kb + i * 8 + j;
                float h0 = hsn[0][kk], h1 = hsn[1][kk];
                float wr = bf2f(wr8[j]), wz = bf2f(wz8[j]), wn = bf2f(wn8[j]);
                a[0] += h0 * wr; a[1] += h0 * wz; a[2] += h0 * wn;
                a[3] += h1 * wr; a[4] += h1 * wz; a[5] += h1 * wn;
            }
        }
    }
#pragma unroll
    for (int i = 0; i < 6; ++i) part[half][f][i] = a[i];
    __syncthreads();
    // ---- gates for own node (node = n0+half), all inputs local
    {
        int node = n0 + half;
        float ghr = part[0][f][half * 3 + 0] + part[1][f][half * 3 + 0] + b_hh[f];
        float ghz = part[0][f][half * 3 + 1] + part[1][f][half * 3 + 1] + b_hh[128 + f];
        float ghn = part[0][f][half * 3 + 2] + part[1][f][half * 3 + 2] + b_hh[256 + f];
        size_t gib = ((size_t)node * T_STEPS + t_next) * F3;
        float hv = hsn[half][f];
        float rr = 1.f / (1.f + expf(-(GI[gib + f] + ghr)));
        float zz = 1.f / (1.f + expf(-(GI[gib + 128 + f] + ghz)));
        float nn = tanhf(GI[gib + 256 + f] + rr * ghn);
        float g  = (1.f - zz) * nn + zz * hv;
        g_out[node * F_DIM + f] = g;
        float inv = __expf(-(float)node * (9.210340371976184f / 64.0f));
        float ang = (float)t_next * inv;
        float pe  = ((t_next & 1) == 0) ? sinf(ang) : cosf(ang);
        Hm[((size_t)node * T_STEPS + t_next) * F_DIM + f] = g + pe;
    }
}

// ================================================================ 128x128-tile bf16 MFMA GEMM core (B is [P,K])
template <bool RELU, bool ABF16, bool BF16OUT>
__global__ __launch_bounds__(256) void mfma_gemm128(const void* __restrict__ Aptr,
                                                    const float* __restrict__ B,
                                                    const float* __restrict__ bias,
                                                    void* __restrict__ Cptr,
                                                    int M, int K, int P) {
    __shared__ short As[128][40];
    __shared__ short Bs[128][40];
    int tid = threadIdx.x;
    int p0 = blockIdx.x * 128, row0 = blockIdx.y * 128;
    int lane = tid & 63, w = tid >> 6, col = lane & 15, quad = lane >> 4;
    int qr = w >> 1, qc = w & 1;
    f32x4 acc[4][4];
#pragma unroll
    for (int j = 0; j < 4; ++j)
#pragma unroll
        for (int jj = 0; jj < 4; ++jj) acc[j][jj] = (f32x4){0.f, 0.f, 0.f, 0.f};

    for (int k0 = 0; k0 < K; k0 += 32) {
        if (ABF16) {
            const short* A = (const short*)Aptr;
#pragma unroll
            for (int i = 0; i < 2; ++i) {
                int idx = tid * 2 + i;              // 512 chunks of 8 shorts
                int r = idx >> 2, c8 = (idx & 3) * 8;
                *(int4*)&As[r][c8] = *(const int4*)(A + (size_t)(row0 + r) * K + k0 + c8);
            }
        } else {
            const float* A = (const float*)Aptr;
#pragma unroll
            for (int i = 0; i < 4; ++i) {
                int idx = tid * 4 + i;
                int r = idx >> 3, c4 = (idx & 7) << 2;
                const float4 f4 = *(const float4*)(A + (size_t)(row0 + r) * K + k0 + c4);
                union { __hip_bfloat162 h2[2]; short4 s4; } u;
                u.h2[0] = __float22bfloat162_rn(make_float2(f4.x, f4.y));
                u.h2[1] = __float22bfloat162_rn(make_float2(f4.z, f4.w));
                *(short4*)&As[r][c4] = u.s4;
            }
        }
#pragma unroll
        for (int i = 0; i < 4; ++i) {
            int idx = tid * 4 + i;
            int r = idx >> 3, c4 = (idx & 7) << 2;
            const float4 f4 = *(const float4*)(B + (size_t)(p0 + r) * K + k0 + c4);
            union { __hip_bfloat162 h2[2]; short4 s4; } u;
            u.h2[0] = __float22bfloat162_rn(make_float2(f4.x, f4.y));
            u.h2[1] = __float22bfloat162_rn(make_float2(f4.z, f4.w));
            *(short4*)&Bs[r][c4] = u.s4;
        }
        __syncthreads();
        bf16x8 af[4], bfr[4];
#pragma unroll
        for (int j = 0; j < 4; ++j) af[j]  = *(const bf16x8*)&As[qr * 64 + j * 16 + col][quad * 8];
#pragma unroll
        for (int j = 0; j < 4; ++j) bfr[j] = *(const bf16x8*)&Bs[qc * 64 + j * 16 + col][quad * 8];
#pragma unroll
        for (int j = 0; j < 4; ++j)
#pragma unroll
            for (int jj = 0; jj < 4; ++jj)
                acc[j][jj] = __builtin_amdgcn_mfma_f32_16x16x32_bf16(af[j], bfr[jj], acc[j][jj], 0, 0, 0);
        __syncthreads();
    }
#pragma unroll
    for (int j = 0; j < 4; ++j) {
#pragma unroll
        for (int jj = 0; jj < 4; ++jj) {
            int cg = p0 + qc * 64 + jj * 16 + col;
            float bvv = bias ? bias[cg] : 0.f;
#pragma unroll
            for (int r = 0; r < 4; ++r) {
                int rg = row0 + qr * 64 + j * 16 + quad * 4 + r;
                float v = acc[j][jj][r] + bvv;
                if (RELU) v = fmaxf(v, 0.f);
                if (BF16OUT) ((short*)Cptr)[(size_t)rg * P + cg] = f2bf(v);
                else         ((float*)Cptr)[(size_t)rg * P + cg] = v;
            }
        }
    }
}

// qkv variant: same 128x128 core, epilogue writes bf16 Qb/Kb/Vb all in [T*H,N,D] (q scaled)
__global__ __launch_bounds__(256) void qkv_gemm128(const float* __restrict__ A,
                                                   const float* __restrict__ B,
                                                   const float* __restrict__ bias,
                                                   short* __restrict__ Qb,
                                                   short* __restrict__ Kb,
                                                   short* __restrict__ Vb) {
    __shared__ short As[128][40];
    __shared__ short Bs[128][40];
    int tid = threadIdx.x;
    int p0 = blockIdx.x * 128, row0 = blockIdx.y * 128;
    int lane = tid & 63, w = tid >> 6, col = lane & 15, quad = lane >> 4;
    int qr = w >> 1, qc = w & 1;
    const int K = F_DIM;
    f32x4 acc[4][4];
#pragma unroll
    for (int j = 0; j < 4; ++j)
#pragma unroll
        for (int jj = 0; jj < 4; ++jj) acc[j][jj] = (f32x4){0.f, 0.f, 0.f, 0.f};

    for (int k0 = 0; k0 < K; k0 += 32) {
#pragma unroll
        for (int i = 0; i < 4; ++i) {
            int idx = tid * 4 + i;
            int r = idx >> 3, c4 = (idx & 7) << 2;
            const float4 f4 = *(const float4*)(A + (size_t)(row0 + r) * K + k0 + c4);
            union { __hip_bfloat162 h2[2]; short4 s4; } u;
            u.h2[0] = __float22bfloat162_rn(make_float2(f4.x, f4.y));
            u.h2[1] = __float22bfloat162_rn(make_float2(f4.z, f4.w));
            *(short4*)&As[r][c4] = u.s4;
        }
#pragma unroll
        for (int i = 0; i < 4; ++i) {
            int idx = tid * 4 + i;
            int r = idx >> 3, c4 = (idx & 7) << 2;
            const float4 f4 = *(const float4*)(B + (size_t)(p0 + r) * K + k0 + c4);
            union { __hip_bfloat162 h2[2]; short4 s4; } u;
            u.h2[0] = __float22bfloat162_rn(make_float2(f4.x, f4.y));
            u.h2[1] = __float22bfloat162_rn(make_float2(f4.z, f4.w));
            *(short4*)&Bs[r][c4] = u.s4;
        }
        __syncthreads();
        bf16x8 af[4], bfr[4];
#pragma unroll
        for (int j = 0; j < 4; ++j) af[j]  = *(const bf16x8*)&As[qr * 64 + j * 16 + col][quad * 8];
#pragma unroll
        for (int j = 0; j < 4; ++j) bfr[j] = *(const bf16x8*)&Bs[qc * 64 + j * 16 + col][quad * 8];
#pragma unroll
        for (int j = 0; j < 4; ++j)
#pragma unroll
            for (int jj = 0; jj < 4; ++jj)
                acc[j][jj] = __builtin_amdgcn_mfma_f32_16x16x32_bf16(af[j], bfr[jj], acc[j][jj], 0, 0, 0);
        __syncthreads();
    }
#pragma unroll
    for (int j = 0; j < 4; ++j) {
#pragma unroll
        for (int jj = 0; jj < 4; ++jj) {
            int cg = p0 + qc * 64 + jj * 16 + col;
            int which = cg >> 7, f = cg & 127;
            int hh = f >> 5, d = f & 31;
            float bv = bias[cg];
#pragma unroll
            for (int r = 0; r < 4; ++r) {
                int rg = row0 + qr * 64 + j * 16 + quad * 4 + r;
                int n = rg >> 5, t = rg & 31;
                int th = t * H_HEADS + hh;
                size_t dst = ((size_t)th * N_NODES + n) * D_HEAD + d;
                float v = acc[j][jj][r] + bv;
                if (which == 0)      Qb[dst] = f2bf(v * 0.17677669529663687f);
                else if (which == 1) Kb[dst] = f2bf(v);
                else                 Vb[dst] = f2bf(v);
            }
        }
    }
}

// ---------------------------------------------------------------- V transpose: Vb [T*H,N,D] -> VTb [T*H,D,N], coalesced
__global__ __launch_bounds__(256) void vtrans(const short* __restrict__ Vb,
                                              short* __restrict__ VTb) {
    __shared__ short tile[32][36];
    int th = blockIdx.x;
    int n0 = blockIdx.y * 32;
    int tid = threadIdx.x;
    {
        int n_i = tid >> 3, d0 = (tid & 7) * 4;
        *(short4*)&tile[n_i][d0] =
            *(const short4*)(Vb + ((size_t)th * N_NODES + n0 + n_i) * D_HEAD + d0);
    }
    __syncthreads();
    {
        int d = tid >> 3, m0 = (tid & 7) * 4;
        short4 o;
        o.x = tile[m0 + 0][d]; o.y = tile[m0 + 1][d];
        o.z = tile[m0 + 2][d]; o.w = tile[m0 + 3][d];
        *(short4*)(VTb + ((size_t)th * D_HEAD + d) * N_NODES + n0 + m0) = o;
    }
}

// ---------------------------------------------------------------- MFMA flash attention, 4 waves/block sharing K/V via LDS
// Staging now one 16B store per thread (threads 0-127: K, 128-255: V) —
// start banks <=2-way (free), half the staging instructions.
__global__ __launch_bounds__(256) void attn_mfma(const short* __restrict__ Qb,
                                                 const short* __restrict__ Kb,
                                                 const short* __restrict__ VTb,
                                                 float* __restrict__ ctx) {
    int th = blockIdx.x;
    int t = th >> 2, hh = th & 3;
    int q0 = blockIdx.y * 64;
    int tid = threadIdx.x;
    int w = tid >> 6, lane = tid & 63;
    int col = lane & 15, quad = lane >> 4;
    __shared__ short    Ks[32][40];       // row stride 80B (16B-aligned)
    __shared__ short    Vs[32][40];
    __shared__ unsigned Ps[4][16][20];    // dwords; row stride 80B

    bf16x8 qf = *(const bf16x8*)(Qb + ((size_t)th * N_NODES + q0 + w * 16 + col) * D_HEAD + quad * 8);
    const short* Kbase = Kb  + (size_t)th * (N_NODES * D_HEAD);
    const short* Vbase = VTb + (size_t)th * (D_HEAD * N_NODES);

    int sid  = tid & 127;                  // staging index
    int lrw  = sid >> 2;                   // row 0..31
    int lc4  = (sid & 3) * 8;              // 16B chunk (8 shorts)
    int kperm = ((lrw & 15) << 1) | (lrw >> 4);   // rows 0..15 -> even m, 16..31 -> odd m
    bool doK = tid < 128;

    f32x4 o0 = {0.f, 0.f, 0.f, 0.f}, o1 = {0.f, 0.f, 0.f, 0.f};
    float l0 = 0.f, l1 = 0.f, l2 = 0.f, l3 = 0.f;
    const f32x4 zc = {0.f, 0.f, 0.f, 0.f};

    for (int mt = 0; mt < 32; ++mt) {
        int m0 = mt * 32;
        __syncthreads();   // WAR: previous iteration's Ks/Vs reads done
        if (doK)
            *(ush8*)&Ks[lrw][lc4] = *(const ush8*)(Kbase + (size_t)(m0 + kperm) * D_HEAD + lc4);
        else
            *(ush8*)&Vs[lrw][lc4] = *(const ush8*)(Vbase + (size_t)lrw * N_NODES + m0 + lc4);
        __syncthreads();   // tiles visible
        bf16x8 k0 = *(const bf16x8*)&Ks[col][quad * 8];        // K[m0+2col]
        bf16x8 k1 = *(const bf16x8*)&Ks[col + 16][quad * 8];   // K[m0+2col+1]
        f32x4 s0 = __builtin_amdgcn_mfma_f32_16x16x32_bf16(qf, k0, zc, 0, 0, 0);
        f32x4 s1 = __builtin_amdgcn_mfma_f32_16x16x32_bf16(qf, k1, zc, 0, 0, 0);
        float ps[4][2];
#pragma unroll
        for (int r = 0; r < 4; ++r) {
            ps[r][0] = __expf(s0[r]);
            ps[r][1] = __expf(s1[r]);
            union { __hip_bfloat162 h; unsigned u; } u;
            u.h = __float22bfloat162_rn(make_float2(ps[r][0], ps[r][1]));
            Ps[w][quad * 4 + r][col] = u.u;   // natural m order
        }
        l0 += ps[0][0] + ps[0][1]; l1 += ps[1][0] + ps[1][1];
        l2 += ps[2][0] + ps[2][1]; l3 += ps[3][0] + ps[3][1];
        __builtin_amdgcn_s_waitcnt(0xC07F);   // lgkmcnt(0): own Ps writes committed
        bf16x8 pf = *(const bf16x8*)&Ps[w][col][quad * 4];     // A-frag, natural m order
        bf16x8 v0 = *(const bf16x8*)&Vs[col][quad * 8];        // V^T[d=col][m0+quad*8..]
        bf16x8 v1 = *(const bf16x8*)&Vs[col + 16][quad * 8];
        o0 = __builtin_amdgcn_mfma_f32_16x16x32_bf16(pf, v0, o0, 0, 0, 0);
        o1 = __builtin_amdgcn_mfma_f32_16x16x32_bf16(pf, v1, o1, 0, 0, 0);
    }
    float lr[4] = {l0, l1, l2, l3};
#pragma unroll
    for (int r = 0; r < 4; ++r) {
        float s = lr[r];
        s += __shfl_xor(s, 1); s += __shfl_xor(s, 2);
        s += __shfl_xor(s, 4); s += __shfl_xor(s, 8);
        lr[r] = 1.f / s;
    }
#pragma unroll
    for (int r = 0; r < 4; ++r) {
        int n = q0 + w * 16 + quad * 4 + r;
        size_t base = ((size_t)n * T_STEPS + t) * F_DIM + hh * D_HEAD;
        ctx[base + col]      = o0[r] * lr[r];
        ctx[base + 16 + col] = o1[r] * lr[r];
    }
}

// ---------------------------------------------------------------- LayerNorm over F=128, 4 rows/block, optional residual
__global__ __launch_bounds__(256) void ln_kernel(
        const float* __restrict__ a, const float* __restrict__ resid,
        const float* __restrict__ gamma, const float* __restrict__ beta,
        float* __restrict__ out) {
    int row = blockIdx.x * 4 + (threadIdx.x >> 6);
    int tid = threadIdx.x & 63;
    int base = row * F_DIM;
    float x0 = a[base + tid], x1 = a[base + 64 + tid];
    if (resid) { x0 += resid[base + tid]; x1 += resid[base + 64 + tid]; }
    float s = x0 + x1;
#pragma unroll
    for (int o = 32; o > 0; o >>= 1) s += __shfl_xor(s, o);
    float mu = s * (1.f / 128.f);
    float d0 = x0 - mu, d1 = x1 - mu;
    float v = d0 * d0 + d1 * d1;
#pragma unroll
    for (int o = 32; o > 0; o >>= 1) v += __shfl_xor(v, o);
    float inv = rsqrtf(v * (1.f / 128.f) + 1e-5f);
    out[base + tid]      = d0 * inv * gamma[tid] + beta[tid];
    out[base + 64 + tid] = d1 * inv * gamma[64 + tid] + beta[64 + tid];
}

// fused LN2 + LNF: enc = LN(LN(a+resid; g2,b2); gf,bf) — x2 never materialized
__global__ __launch_bounds__(256) void ln2_lnf_kernel(
        const float* __restrict__ a, const float* __restrict__ resid,
        const float* __restrict__ g2, const float* __restrict__ b2,
        const float* __restrict__ gf, const float* __restrict__ bfp,
        float* __restrict__ out) {
    int row = blockIdx.x * 4 + (threadIdx.x >> 6);
    int tid = threadIdx.x & 63;
    int base = row * F_DIM;
    float x0 = a[base + tid] + resid[base + tid];
    float x1 = a[base + 64 + tid] + resid[base + 64 + tid];
    float s = x0 + x1;
#pragma unroll
    for (int o = 32; o > 0; o >>= 1) s += __shfl_xor(s, o);
    float mu = s * (1.f / 128.f);
    float d0 = x0 - mu, d1 = x1 - mu;
    float v = d0 * d0 + d1 * d1;
#pragma unroll
    for (int o = 32; o > 0; o >>= 1) v += __shfl_xor(v, o);
    float inv = rsqrtf(v * (1.f / 128.f) + 1e-5f);
    float y0 = d0 * inv * g2[tid] + b2[tid];
    float y1 = d1 * inv * g2[64 + tid] + b2[64 + tid];
    s = y0 + y1;
#pragma unroll
    for (int o = 32; o > 0; o >>= 1) s += __shfl_xor(s, o);
    mu = s * (1.f / 128.f);
    d0 = y0 - mu; d1 = y1 - mu;
    v = d0 * d0 + d1 * d1;
#pragma unroll
    for (int o = 32; o > 0; o >>= 1) v += __shfl_xor(v, o);
    inv = rsqrtf(v * (1.f / 128.f) + 1e-5f);
    out[base + tid]      = d0 * inv * gf[tid] + bfp[tid];
    out[base + 64 + tid] = d1 * inv * gf[64 + tid] + bfp[64 + tid];
}

// ---------------------------------------------------------------- 64x64 bf16 MFMA GEMM
template <bool TB, bool RELU, bool SPLITK, bool ABF16>
__global__ __launch_bounds__(256) void mfma_gemm(const void* __restrict__ Aptr,
                                                 const float* __restrict__ B,
                                                 const float* __restrict__ bias,
                                                 float* __restrict__ C,
                                                 int M, int K, int P, int Kc) {
    __shared__ short As[64][40];
    __shared__ short Bs[64][40];
    int tid = threadIdx.x;
    int p0 = blockIdx.x * 64, row0 = blockIdx.y * 64;
    int k_begin = SPLITK ? blockIdx.z * Kc : 0;
    int k_end   = SPLITK ? k_begin + Kc : K;
    int lane = tid & 63, w = tid >> 6, col = lane & 15, quad = lane >> 4;
    f32x4 acc[4];
#pragma unroll
    for (int j = 0; j < 4; ++j) acc[j] = (f32x4){0.f, 0.f, 0.f, 0.f};

    for (int k0 = k_begin; k0 < k_end; k0 += 32) {
        if (ABF16) {
            const short* A = (const short*)Aptr;
            int r = tid >> 2, c8 = (tid & 3) * 8;
            *(int4*)&As[r][c8] = *(const int4*)(A + (size_t)(row0 + r) * K + k0 + c8);
        } else {
            const float* A = (const float*)Aptr;
#pragma unroll
            for (int i = 0; i < 2; ++i) {
                int idx = tid * 2 + i;
                int r = idx >> 3, c4 = (idx & 7) << 2;
                const float4 f4 = *(const float4*)(A + (size_t)(row0 + r) * K + k0 + c4);
                union { __hip_bfloat162 h2[2]; short4 s4; } u;
                u.h2[0] = __float22bfloat162_rn(make_float2(f4.x, f4.y));
                u.h2[1] = __float22bfloat162_rn(make_float2(f4.z, f4.w));
                *(short4*)&As[r][c4] = u.s4;
            }
        }
        if (TB) {
#pragma unroll
            for (int i = 0; i < 2; ++i) {
                int idx = tid * 2 + i;
                int r = idx >> 3, c4 = (idx & 7) << 2;
                const float4 f4 = *(const float4*)(B + (size_t)(p0 + r) * K + k0 + c4);
                union { __hip_bfloat162 h2[2]; short4 s4; } u;
                u.h2[0] = __float22bfloat162_rn(make_float2(f4.x, f4.y));
                u.h2[1] = __float22bfloat162_rn(make_float2(f4.z, f4.w));
                *(short4*)&Bs[r][c4] = u.s4;
            }
        } else {
#pragma unroll
            for (int i = 0; i < 2; ++i) {
                int idx = tid * 2 + i;
                int kk = idx >> 4, c4 = (idx & 15) << 2;
                const float4 f4 = *(const float4*)(B + (size_t)(k0 + kk) * P + p0 + c4);
                Bs[c4 + 0][kk] = f2bf(f4.x);
                Bs[c4 + 1][kk] = f2bf(f4.y);
                Bs[c4 + 2][kk] = f2bf(f4.z);
                Bs[c4 + 3][kk] = f2bf(f4.w);
            }
        }
        __syncthreads();
        bf16x8 af = *(const bf16x8*)&As[w * 16 + col][quad * 8];
#pragma unroll
        for (int j = 0; j < 4; ++j) {
            bf16x8 bv = *(const bf16x8*)&Bs[j * 16 + col][quad * 8];
            acc[j] = __builtin_amdgcn_mfma_f32_16x16x32_bf16(af, bv, acc[j], 0, 0, 0);
        }
        __syncthreads();
    }
    size_t zoff = SPLITK ? (size_t)blockIdx.z * M * P : 0;
#pragma unroll
    for (int j = 0; j < 4; ++j) {
        int cg_ = p0 + j * 16 + col;
        float bvv = (!SPLITK && bias) ? bias[cg_] : 0.f;
#pragma unroll
        for (int r = 0; r < 4; ++r) {
            int rg = row0 + w * 16 + quad * 4 + r;
            float v = acc[j][r] + bvv;
            if (!SPLITK && RELU) v = fmaxf(v, 0.f);
            C[zoff + (size_t)rg * P + cg_] = v;
        }
    }
}

// ---------------------------------------------------------------- launch
extern "C" void kernel_launch(void* const* d_in, const int* in_sizes, int n_in,
                              void* d_out, int out_size, void* d_ws, size_t ws_size,
                              hipStream_t stream) {
    const int*   A_cols     = (const int*)d_in[1];
    const float* A_vals     = (const float*)d_in[2];
    const float* X          = (const float*)d_in[3];
    const float* W_gcn      = (const float*)d_in[4];
    const float* W_ih       = (const float*)d_in[5];
    const float* W_hh       = (const float*)d_in[6];
    const float* b_ih       = (const float*)d_in[7];
    const float* b_hh       = (const float*)d_in[8];
    const float* in_proj_w  = (const float*)d_in[9];
    const float* in_proj_b  = (const float*)d_in[10];
    const float* out_proj_w = (const float*)d_in[11];
    const float* out_proj_b = (const float*)d_in[12];
    const float* ln1_g = (const float*)d_in[13];
    const float* ln1_b = (const float*)d_in[14];
    const float* ln2_g = (const float*)d_in[15];
    const float* ln2_b = (const float*)d_in[16];
    const float* lnf_g = (const float*)d_in[17];
    const float* lnf_b = (const float*)d_in[18];
    const float* ff1_w = (const float*)d_in[19];
    const float* ff1_b = (const float*)d_in[20];
    const float* ff2_w = (const float*)d_in[21];
    const float* ff2_b = (const float*)d_in[22];
    const float* fc1_w = (const float*)d_in[23];
    const float* fc1_b = (const float*)d_in[24];
    const float* fc2_w = (const float*)d_in[25];
    const float* fc2_b = (const float*)d_in[26];
    const float* fc3_w = (const float*)d_in[27];
    const float* fc3_b = (const float*)d_in[28];
    float* out = (float*)d_out;
    float* ws  = (float*)d_ws;

    const size_t o_Hm = 0;
    const size_t o_A  = o_Hm + 4194304;
    const size_t o_B  = o_A + 4194304;
    const size_t o_C  = o_B + 4194304;           // GI -> ff_hid(bf16)
    const size_t o_D  = o_C + 12582912;          // Qb/Kb/VTb/Vb bf16 -> head partials
    const size_t o_WT = o_D + 12582912;          // bf16 weights (scan)
    const size_t o_h  = o_WT + 49152;
    const size_t o_g  = o_h + 131072;
    const size_t o_h1 = o_g + 131072;
    const size_t o_h2 = o_h1 + 524288;

    float* Hm    = ws + o_Hm;
    float* bufA  = ws + o_A;
    short* Xs    = (short*)bufA;                 // X_s bf16 [N, TF] (dead after step 2)
    float* bufB  = ws + o_B;
    float* bufC  = ws + o_C;
    short* ffh   = (short*)bufC;                 // ff_hid bf16 [NT, 512]
    short* Qb    = (short*)(ws + o_D);
    short* Kb    = Qb + 4194304;
    short* VTb   = Kb + 4194304;
    short* Vb    = VTb + 4194304;
    float* partbuf = ws + o_D;                   // head partials (o_D dead after attn)
    unsigned short* Whh_bf = (unsigned short*)(ws + o_WT);   // 49152 ushort
    unsigned short* WgT_bf = Whh_bf + 49152;                 // 16384 ushort
    float* g0    = ws + o_g;
    float* h1    = ws + o_h1;
    float* h2    = ws + o_h2;
    float* g1    = h2;                           // alias: h2 dead during scan

    // 1. X_s = A_hat @ X -> Xs (bf16); c-slice-major dispatch for L2 locality
    spmm_wide<<<dim3(1024, 16), 256, 0, stream>>>(A_cols, A_vals, X, Xs);
    // 2. X_tilde = relu(X_s @ W_gcn) -> bufB  (bf16 A)
    mfma_gemm<false, true, false, true><<<dim3(2, 512), 256, 0, stream>>>(Xs, W_gcn, nullptr, bufB, NT, F_DIM, F_DIM, 0);
    // 3. GI = X_tilde @ W_ih^T + b_ih -> bufC  (128-tile)
    mfma_gemm128<false, false, false><<<dim3(3, 256), 256, 0, stream>>>(bufB, W_ih, b_ih, bufC, NT, F_DIM, F3);
    // 4. bf16 weight prep (scan; per-thread-contiguous layouts)
    prep_weights<<<192, 256, 0, stream>>>(W_hh, W_gcn, Whh_bf, WgT_bf);
    // 5. g(0), Hm[:,0]  (h0=0, GH0=0 algebraically)
    gates0_kernel<<<512, 256, 0, stream>>>(bufC, b_hh, g0, Hm);
    // 6. fused scan: one launch per step; h/GH stay on-chip (512 blocks = 2/CU)
    for (int s = 0; s < T_STEPS - 1; ++s) {
        const float* gi = (s & 1) ? g1 : g0;
        float*       go = (s & 1) ? g0 : g1;
        scan_step<<<512, 256, 0, stream>>>(A_cols, A_vals, gi, WgT_bf, Whh_bf, b_hh, bufC, go, Hm, s + 1);
    }
    // 7. qkv projection (128-tile) -> Qb/Kb/Vb (all K-layout)
    qkv_gemm128<<<dim3(3, 256), 256, 0, stream>>>(Hm, in_proj_w, in_proj_b, Qb, Kb, Vb);
    // 7b. V transpose through LDS (coalesced both sides)
    vtrans<<<dim3(128, 32), 256, 0, stream>>>(Vb, VTb);
    // 8. MFMA attention -> ctx (bufA)
    attn_mfma<<<dim3(128, 16), 256, 0, stream>>>(Qb, Kb, VTb, bufA);
    // 9. attn_out = ctx @ out_proj_w^T + b -> bufB
    mfma_gemm<true, false, false, false><<<dim3(2, 512), 256, 0, stream>>>(bufA, out_proj_w, out_proj_b, bufB, NT, F_DIM, F_DIM, 0);
    // 10. x1 = LN(Hm + attn_out) -> bufA
    ln_kernel<<<NT / 4, 256, 0, stream>>>(Hm, bufB, ln1_g, ln1_b, bufA);
    // 11. ff_hid = relu(x1 @ ff1_w^T + b) -> ffh (bf16, 128-tile)
    mfma_gemm128<true, false, true><<<dim3(4, 256), 256, 0, stream>>>(bufA, ff1_w, ff1_b, ffh, NT, F_DIM, HID);
    // 12. ff_out = ff_hid @ ff2_w^T + b -> bufB  (64-tile, bf16 A, 1024 blocks)
    mfma_gemm<true, false, false, true><<<dim3(2, 512), 256, 0, stream>>>(ffh, ff2_w, ff2_b, bufB, NT, HID, F_DIM, 0);
    // 13+14. enc = LN(LN(x1 + ff_out)) -> bufA  (fused)
    ln2_lnf_kernel<<<NT / 4, 256, 0, stream>>>(bufA, bufB, ln2_g, ln2_b, lnf_g, lnf_b, bufA);
    // 15. h1 = relu(enc_flat @ fc1_w^T + b)  — split-K=4 partials + reduce
    mfma_gemm<true, false, true, false><<<dim3(8, 16, 4), 256, 0, stream>>>(bufA, fc1_w, nullptr, partbuf, N_NODES, TF, HID, 1024);
    reduce_bias<true><<<2048, 256, 0, stream>>>(partbuf, 4, 524288, fc1_b, HID, h1);
    // 16. h2 = relu(h1 @ fc2_w^T + b) — split-K=4 partials + reduce
    mfma_gemm<true, false, true, false><<<dim3(8, 16, 4), 256, 0, stream>>>(h1, fc2_w, nullptr, partbuf, N_NODES, HID, HID, 128);
    reduce_bias<true><<<2048, 256, 0, stream>>>(partbuf, 4, 524288, fc2_b, HID, h2);
    // 17. out = h2 @ fc3_w^T + b — split-K=8 partials + reduce
    mfma_gemm<true, false, true, false><<<dim3(1, 16, 8), 256, 0, stream>>>(h2, fc3_w, nullptr, partbuf, N_NODES, HID, OUT_DIM, 64);
    reduce_bias<false><<<256, 256, 0, stream>>>(partbuf, 8, 65536, fc3_b, OUT_DIM, out);
}

// Round 14
// 742.850 us; speedup vs baseline: 1.1516x; 1.1516x over previous
//
#include <hip/hip_runtime.h>
#include <hip/hip_bf16.h>
#include <math.h>

#define N_NODES 1024
#define T_STEPS 32
#define F_DIM   128
#define H_HEADS 4
#define D_HEAD  32
#define DEG     32
#define HID     512
#define OUT_DIM 64
#define TF      (T_STEPS * F_DIM)   // 4096
#define NT      (N_NODES * T_STEPS) // 32768
#define F3      (3 * F_DIM)         // 384

typedef __attribute__((ext_vector_type(8))) __bf16 bf16x8;
typedef __attribute__((ext_vector_type(4))) float  f32x4;

// float -> bf16 bits, round-to-nearest-even (scalar fallback)
__device__ __forceinline__ short f2bf(float x) {
    union { float f; unsigned u; } v; v.f = x;
    unsigned r = (v.u + 0x7FFFu + ((v.u >> 16) & 1u)) >> 16;
    return (short)r;
}
__device__ __forceinline__ float bf2f(unsigned short b) {
    union { unsigned u; float f; } v; v.u = ((unsigned)b) << 16; return v.f;
}

// ---------------------------------------------------------------- utilities
// one-time: W_hh [384,128] -> bf16 WhhT [128,384]; W_gcn [128,128] -> bf16 (same layout)
__global__ void prep_weights(const float* __restrict__ W_hh, const float* __restrict__ W_gcn,
                             unsigned short* __restrict__ WhhT_bf,
                             unsigned short* __restrict__ Wg_bf) {
    int idx = blockIdx.x * 256 + threadIdx.x;
    if (idx < F3 * F_DIM) {
        int j = idx / F_DIM;   // 0..383
        int k = idx % F_DIM;   // 0..127
        WhhT_bf[k * F3 + j] = (unsigned short)f2bf(W_hh[idx]);
    }
    if (idx < F_DIM * F_DIM) {
        Wg_bf[idx] = (unsigned short)f2bf(W_gcn[idx]);
    }
}

// split-K partial reduction + bias (+relu)
template <bool RELU>
__global__ void reduce_bias(const float* __restrict__ part, int nz, int MP,
                            const float* __restrict__ bias, int P,
                            float* __restrict__ C) {
    int i = blockIdx.x * 256 + threadIdx.x;
    if (i < MP) {
        float v = bias[i & (P - 1)];
        for (int z = 0; z < nz; ++z) v += part[(size_t)z * MP + i];
        if (RELU) v = fmaxf(v, 0.f);
        C[i] = v;
    }
}

// ---------------------------------------------------------------- SpMM (wide): Y[n, :] = sum_e vals * X[cols[e], :]
__global__ void spmm_wide(const int* __restrict__ cols, const float* __restrict__ vals,
                          const float* __restrict__ X, short* __restrict__ Y) {
    int n = blockIdx.x;
    int c = blockIdx.y * 256 + threadIdx.x;
    const int*   ce = cols + n * DEG;
    const float* ve = vals + n * DEG;
    float acc = 0.f;
#pragma unroll
    for (int e = 0; e < DEG; ++e) acc += ve[e] * X[(size_t)ce[e] * TF + c];
    Y[(size_t)n * TF + c] = f2bf(acc);
}

// ---------------------------------------------------------------- t=0 gates: h=0, GH=0 algebraically; pe(t=0)=sin(0)=0
__global__ __launch_bounds__(256) void gates0_kernel(
        const float* __restrict__ GI, const float* __restrict__ b_hh,
        float* __restrict__ g_out, float* __restrict__ Hm) {
    int idx = blockIdx.x * 256 + threadIdx.x;   // over N*F
    int n = idx >> 7, f = idx & 127;
    size_t gib = (size_t)n * T_STEPS * F3;
    float rr = 1.f / (1.f + expf(-(GI[gib + f] + b_hh[f])));
    float zz = 1.f / (1.f + expf(-(GI[gib + 128 + f] + b_hh[128 + f])));
    float nn = tanhf(GI[gib + 256 + f] + rr * b_hh[256 + f]);
    float g  = (1.f - zz) * nn;
    g_out[idx] = g;
    Hm[(size_t)n * T_STEPS * F_DIM + f] = g;    // pe = 0 at t=0
}

// ---------------------------------------------------------------- fully fused scan step, 2 nodes/block (512 blocks)
// Weight reads are scalar-per-thread but wave-coalesced (64 lanes x 2B = one line).
__global__ __launch_bounds__(256) void scan_step(
        const int* __restrict__ cols, const float* __restrict__ vals,
        const float* __restrict__ g_in, const unsigned short* __restrict__ Wg_bf,
        const unsigned short* __restrict__ WhhT_bf, const float* __restrict__ b_hh,
        const float* __restrict__ GI, float* __restrict__ g_out,
        float* __restrict__ Hm, int t_next) {
    __shared__ float sp[2][F_DIM];
    __shared__ float hsn[2][F_DIM];
    __shared__ float part[2][F_DIM][8];    // 6 used, +2 pad
    __shared__ float gpart[2][2][F_DIM];
    int tid = threadIdx.x;
    int n0 = blockIdx.x * 2;
    int f = tid & 127, half = tid >> 7;
    // ---- SpMM: edges split across halves
    float b0 = 0.f, b1 = 0.f;
    int eb = half * 16;
#pragma unroll
    for (int e = 0; e < 16; ++e) {
        int i0 = n0 * DEG + eb + e;
        int i1 = (n0 + 1) * DEG + eb + e;
        b0 += vals[i0] * g_in[cols[i0] * F_DIM + f];
        b1 += vals[i1] * g_in[cols[i1] * F_DIM + f];
    }
    gpart[half][0][f] = b0; gpart[half][1][f] = b1;
    __syncthreads();
    sp[half][f] = gpart[0][half][f] + gpart[1][half][f];   // half doubles as node idx
    __syncthreads();
    // ---- GCN: k range split across halves (bf16 weights, coalesced)
    float c0 = 0.f, c1 = 0.f;
    int kb = half * 64;
#pragma unroll 4
    for (int k = 0; k < 64; ++k) {
        int kk = kb + k;
        float w = bf2f(Wg_bf[kk * F_DIM + f]);
        c0 += sp[0][kk] * w; c1 += sp[1][kk] * w;
    }
    gpart[half][0][f] = c0; gpart[half][1][f] = c1;
    __syncthreads();
    hsn[half][f] = fmaxf(gpart[0][half][f] + gpart[1][half][f], 0.f);
    __syncthreads();
    // ---- GH = h_new @ W_hh^T : k split, 2 nodes x 3 gates (bf16 weights, coalesced)
    float a[6] = {0.f, 0.f, 0.f, 0.f, 0.f, 0.f};
#pragma unroll 2
    for (int k = 0; k < 64; ++k) {
        int kk = kb + k;
        const unsigned short* w = WhhT_bf + kk * F3;
        float wr = bf2f(w[f]), wz = bf2f(w[128 + f]), wn = bf2f(w[256 + f]);
        float h0 = hsn[0][kk], h1 = hsn[1][kk];
        a[0] += h0 * wr; a[1] += h0 * wz; a[2] += h0 * wn;
        a[3] += h1 * wr; a[4] += h1 * wz; a[5] += h1 * wn;
    }
#pragma unroll
    for (int i = 0; i < 6; ++i) part[half][f][i] = a[i];
    __syncthreads();
    // ---- gates for own node (node = n0+half), all inputs local
    {
        int node = n0 + half;
        float ghr = part[0][f][half * 3 + 0] + part[1][f][half * 3 + 0] + b_hh[f];
        float ghz = part[0][f][half * 3 + 1] + part[1][f][half * 3 + 1] + b_hh[128 + f];
        float ghn = part[0][f][half * 3 + 2] + part[1][f][half * 3 + 2] + b_hh[256 + f];
        size_t gib = ((size_t)node * T_STEPS + t_next) * F3;
        float hv = hsn[half][f];
        float rr = 1.f / (1.f + expf(-(GI[gib + f] + ghr)));
        float zz = 1.f / (1.f + expf(-(GI[gib + 128 + f] + ghz)));
        float nn = tanhf(GI[gib + 256 + f] + rr * ghn);
        float g  = (1.f - zz) * nn + zz * hv;
        g_out[node * F_DIM + f] = g;
        float inv = __expf(-(float)node * (9.210340371976184f / 64.0f));
        float ang = (float)t_next * inv;
        float pe  = ((t_next & 1) == 0) ? sinf(ang) : cosf(ang);
        Hm[((size_t)node * T_STEPS + t_next) * F_DIM + f] = g + pe;
    }
}

// ================================================================ 128x128-tile bf16 MFMA GEMM core (B is [P,K])
template <bool RELU, bool ABF16, bool BF16OUT>
__global__ __launch_bounds__(256) void mfma_gemm128(const void* __restrict__ Aptr,
                                                    const float* __restrict__ B,
                                                    const float* __restrict__ bias,
                                                    void* __restrict__ Cptr,
                                                    int M, int K, int P) {
    __shared__ short As[128][40];
    __shared__ short Bs[128][40];
    int tid = threadIdx.x;
    int p0 = blockIdx.x * 128, row0 = blockIdx.y * 128;
    int lane = tid & 63, w = tid >> 6, col = lane & 15, quad = lane >> 4;
    int qr = w >> 1, qc = w & 1;
    f32x4 acc[4][4];
#pragma unroll
    for (int j = 0; j < 4; ++j)
#pragma unroll
        for (int jj = 0; jj < 4; ++jj) acc[j][jj] = (f32x4){0.f, 0.f, 0.f, 0.f};

    for (int k0 = 0; k0 < K; k0 += 32) {
        if (ABF16) {
            const short* A = (const short*)Aptr;
#pragma unroll
            for (int i = 0; i < 2; ++i) {
                int idx = tid * 2 + i;              // 512 chunks of 8 shorts
                int r = idx >> 2, c8 = (idx & 3) * 8;
                *(int4*)&As[r][c8] = *(const int4*)(A + (size_t)(row0 + r) * K + k0 + c8);
            }
        } else {
            const float* A = (const float*)Aptr;
#pragma unroll
            for (int i = 0; i < 4; ++i) {
                int idx = tid * 4 + i;
                int r = idx >> 3, c4 = (idx & 7) << 2;
                const float4 f4 = *(const float4*)(A + (size_t)(row0 + r) * K + k0 + c4);
                union { __hip_bfloat162 h2[2]; short4 s4; } u;
                u.h2[0] = __float22bfloat162_rn(make_float2(f4.x, f4.y));
                u.h2[1] = __float22bfloat162_rn(make_float2(f4.z, f4.w));
                *(short4*)&As[r][c4] = u.s4;
            }
        }
#pragma unroll
        for (int i = 0; i < 4; ++i) {
            int idx = tid * 4 + i;
            int r = idx >> 3, c4 = (idx & 7) << 2;
            const float4 f4 = *(const float4*)(B + (size_t)(p0 + r) * K + k0 + c4);
            union { __hip_bfloat162 h2[2]; short4 s4; } u;
            u.h2[0] = __float22bfloat162_rn(make_float2(f4.x, f4.y));
            u.h2[1] = __float22bfloat162_rn(make_float2(f4.z, f4.w));
            *(short4*)&Bs[r][c4] = u.s4;
        }
        __syncthreads();
        bf16x8 af[4], bfr[4];
#pragma unroll
        for (int j = 0; j < 4; ++j) af[j]  = *(const bf16x8*)&As[qr * 64 + j * 16 + col][quad * 8];
#pragma unroll
        for (int j = 0; j < 4; ++j) bfr[j] = *(const bf16x8*)&Bs[qc * 64 + j * 16 + col][quad * 8];
#pragma unroll
        for (int j = 0; j < 4; ++j)
#pragma unroll
            for (int jj = 0; jj < 4; ++jj)
                acc[j][jj] = __builtin_amdgcn_mfma_f32_16x16x32_bf16(af[j], bfr[jj], acc[j][jj], 0, 0, 0);
        __syncthreads();
    }
#pragma unroll
    for (int j = 0; j < 4; ++j) {
#pragma unroll
        for (int jj = 0; jj < 4; ++jj) {
            int cg = p0 + qc * 64 + jj * 16 + col;
            float bvv = bias ? bias[cg] : 0.f;
#pragma unroll
            for (int r = 0; r < 4; ++r) {
                int rg = row0 + qr * 64 + j * 16 + quad * 4 + r;
                float v = acc[j][jj][r] + bvv;
                if (RELU) v = fmaxf(v, 0.f);
                if (BF16OUT) ((short*)Cptr)[(size_t)rg * P + cg] = f2bf(v);
                else         ((float*)Cptr)[(size_t)rg * P + cg] = v;
            }
        }
    }
}

// qkv variant: same 128x128 core, epilogue writes bf16 Qb/Kb/Vb all in [T*H,N,D]
// Q scaled by 1/sqrt(D) * log2(e) so attention can use exp2 directly.
__global__ __launch_bounds__(256) void qkv_gemm128(const float* __restrict__ A,
                                                   const float* __restrict__ B,
                                                   const float* __restrict__ bias,
                                                   short* __restrict__ Qb,
                                                   short* __restrict__ Kb,
                                                   short* __restrict__ Vb) {
    __shared__ short As[128][40];
    __shared__ short Bs[128][40];
    int tid = threadIdx.x;
    int p0 = blockIdx.x * 128, row0 = blockIdx.y * 128;
    int lane = tid & 63, w = tid >> 6, col = lane & 15, quad = lane >> 4;
    int qr = w >> 1, qc = w & 1;
    const int K = F_DIM;
    f32x4 acc[4][4];
#pragma unroll
    for (int j = 0; j < 4; ++j)
#pragma unroll
        for (int jj = 0; jj < 4; ++jj) acc[j][jj] = (f32x4){0.f, 0.f, 0.f, 0.f};

    for (int k0 = 0; k0 < K; k0 += 32) {
#pragma unroll
        for (int i = 0; i < 4; ++i) {
            int idx = tid * 4 + i;
            int r = idx >> 3, c4 = (idx & 7) << 2;
            const float4 f4 = *(const float4*)(A + (size_t)(row0 + r) * K + k0 + c4);
            union { __hip_bfloat162 h2[2]; short4 s4; } u;
            u.h2[0] = __float22bfloat162_rn(make_float2(f4.x, f4.y));
            u.h2[1] = __float22bfloat162_rn(make_float2(f4.z, f4.w));
            *(short4*)&As[r][c4] = u.s4;
        }
#pragma unroll
        for (int i = 0; i < 4; ++i) {
            int idx = tid * 4 + i;
            int r = idx >> 3, c4 = (idx & 7) << 2;
            const float4 f4 = *(const float4*)(B + (size_t)(p0 + r) * K + k0 + c4);
            union { __hip_bfloat162 h2[2]; short4 s4; } u;
            u.h2[0] = __float22bfloat162_rn(make_float2(f4.x, f4.y));
            u.h2[1] = __float22bfloat162_rn(make_float2(f4.z, f4.w));
            *(short4*)&Bs[r][c4] = u.s4;
        }
        __syncthreads();
        bf16x8 af[4], bfr[4];
#pragma unroll
        for (int j = 0; j < 4; ++j) af[j]  = *(const bf16x8*)&As[qr * 64 + j * 16 + col][quad * 8];
#pragma unroll
        for (int j = 0; j < 4; ++j) bfr[j] = *(const bf16x8*)&Bs[qc * 64 + j * 16 + col][quad * 8];
#pragma unroll
        for (int j = 0; j < 4; ++j)
#pragma unroll
            for (int jj = 0; jj < 4; ++jj)
                acc[j][jj] = __builtin_amdgcn_mfma_f32_16x16x32_bf16(af[j], bfr[jj], acc[j][jj], 0, 0, 0);
        __syncthreads();
    }
#pragma unroll
    for (int j = 0; j < 4; ++j) {
#pragma unroll
        for (int jj = 0; jj < 4; ++jj) {
            int cg = p0 + qc * 64 + jj * 16 + col;
            int which = cg >> 7, f = cg & 127;
            int hh = f >> 5, d = f & 31;
            float bv = bias[cg];
#pragma unroll
            for (int r = 0; r < 4; ++r) {
                int rg = row0 + qr * 64 + j * 16 + quad * 4 + r;
                int n = rg >> 5, t = rg & 31;
                int th = t * H_HEADS + hh;
                size_t dst = ((size_t)th * N_NODES + n) * D_HEAD + d;
                float v = acc[j][jj][r] + bv;
                if (which == 0)      Qb[dst] = f2bf(v * (0.17677669529663687f * 1.4426950408889634f));
                else if (which == 1) Kb[dst] = f2bf(v);
                else                 Vb[dst] = f2bf(v);
            }
        }
    }
}

// ---------------------------------------------------------------- V transpose: Vb [T*H,N,D] -> VTb [T*H,D,N], coalesced
__global__ __launch_bounds__(256) void vtrans(const short* __restrict__ Vb,
                                              short* __restrict__ VTb) {
    __shared__ short tile[32][36];
    int th = blockIdx.x;
    int n0 = blockIdx.y * 32;
    int tid = threadIdx.x;
    {
        int n_i = tid >> 3, d0 = (tid & 7) * 4;
        *(short4*)&tile[n_i][d0] =
            *(const short4*)(Vb + ((size_t)th * N_NODES + n0 + n_i) * D_HEAD + d0);
    }
    __syncthreads();
    {
        int d = tid >> 3, m0 = (tid & 7) * 4;
        short4 o;
        o.x = tile[m0 + 0][d]; o.y = tile[m0 + 1][d];
        o.z = tile[m0 + 2][d]; o.w = tile[m0 + 3][d];
        *(short4*)(VTb + ((size_t)th * D_HEAD + d) * N_NODES + n0 + m0) = o;
    }
}

// ---------------------------------------------------------------- MFMA flash attention, 4 waves/block sharing K/V via LDS
// Q pre-scaled by log2(e): softmax weights are exp2(s) (normalized, so identical
// up to fp rounding).
__global__ __launch_bounds__(256) void attn_mfma(const short* __restrict__ Qb,
                                                 const short* __restrict__ Kb,
                                                 const short* __restrict__ VTb,
                                                 float* __restrict__ ctx) {
    int th = blockIdx.x;
    int t = th >> 2, hh = th & 3;
    int q0 = blockIdx.y * 64;
    int tid = threadIdx.x;
    int w = tid >> 6, lane = tid & 63;
    int col = lane & 15, quad = lane >> 4;
    __shared__ short    Ks[32][40];       // row stride 80B (16B-aligned)
    __shared__ short    Vs[32][40];
    __shared__ unsigned Ps[4][16][20];    // dwords; row stride 80B

    bf16x8 qf = *(const bf16x8*)(Qb + ((size_t)th * N_NODES + q0 + w * 16 + col) * D_HEAD + quad * 8);
    const short* Kbase = Kb  + (size_t)th * (N_NODES * D_HEAD);
    const short* Vbase = VTb + (size_t)th * (D_HEAD * N_NODES);

    int lrw = tid >> 3;                    // staging row 0..31
    int lc  = (tid & 7) * 4;               // staging col (shorts)
    int kperm = ((lrw & 15) << 1) | (lrw >> 4);   // rows 0..15 -> even m, 16..31 -> odd m

    f32x4 o0 = {0.f, 0.f, 0.f, 0.f}, o1 = {0.f, 0.f, 0.f, 0.f};
    float l0 = 0.f, l1 = 0.f, l2 = 0.f, l3 = 0.f;
    const f32x4 zc = {0.f, 0.f, 0.f, 0.f};

    for (int mt = 0; mt < 32; ++mt) {
        int m0 = mt * 32;
        __syncthreads();   // WAR: previous iteration's Ks/Vs reads done
        *(short4*)&Ks[lrw][lc] = *(const short4*)(Kbase + (size_t)(m0 + kperm) * D_HEAD + lc);
        *(short4*)&Vs[lrw][lc] = *(const short4*)(Vbase + (size_t)lrw * N_NODES + m0 + lc);
        __syncthreads();   // tiles visible
        bf16x8 k0 = *(const bf16x8*)&Ks[col][quad * 8];        // K[m0+2col]
        bf16x8 k1 = *(const bf16x8*)&Ks[col + 16][quad * 8];   // K[m0+2col+1]
        f32x4 s0 = __builtin_amdgcn_mfma_f32_16x16x32_bf16(qf, k0, zc, 0, 0, 0);
        f32x4 s1 = __builtin_amdgcn_mfma_f32_16x16x32_bf16(qf, k1, zc, 0, 0, 0);
        float ps[4][2];
#pragma unroll
        for (int r = 0; r < 4; ++r) {
            ps[r][0] = exp2f(s0[r]);
            ps[r][1] = exp2f(s1[r]);
            union { __hip_bfloat162 h; unsigned u; } u;
            u.h = __float22bfloat162_rn(make_float2(ps[r][0], ps[r][1]));
            Ps[w][quad * 4 + r][col] = u.u;   // natural m order
        }
        l0 += ps[0][0] + ps[0][1]; l1 += ps[1][0] + ps[1][1];
        l2 += ps[2][0] + ps[2][1]; l3 += ps[3][0] + ps[3][1];
        __builtin_amdgcn_s_waitcnt(0xC07F);   // lgkmcnt(0): own Ps writes committed
        bf16x8 pf = *(const bf16x8*)&Ps[w][col][quad * 4];     // A-frag, natural m order
        bf16x8 v0 = *(const bf16x8*)&Vs[col][quad * 8];        // V^T[d=col][m0+quad*8..]
        bf16x8 v1 = *(const bf16x8*)&Vs[col + 16][quad * 8];
        o0 = __builtin_amdgcn_mfma_f32_16x16x32_bf16(pf, v0, o0, 0, 0, 0);
        o1 = __builtin_amdgcn_mfma_f32_16x16x32_bf16(pf, v1, o1, 0, 0, 0);
    }
    float lr[4] = {l0, l1, l2, l3};
#pragma unroll
    for (int r = 0; r < 4; ++r) {
        float s = lr[r];
        s += __shfl_xor(s, 1); s += __shfl_xor(s, 2);
        s += __shfl_xor(s, 4); s += __shfl_xor(s, 8);
        lr[r] = 1.f / s;
    }
#pragma unroll
    for (int r = 0; r < 4; ++r) {
        int n = q0 + w * 16 + quad * 4 + r;
        size_t base = ((size_t)n * T_STEPS + t) * F_DIM + hh * D_HEAD;
        ctx[base + col]      = o0[r] * lr[r];
        ctx[base + 16 + col] = o1[r] * lr[r];
    }
}

// ---------------------------------------------------------------- LayerNorm over F=128, 4 rows/block, optional residual
__global__ __launch_bounds__(256) void ln_kernel(
        const float* __restrict__ a, const float* __restrict__ resid,
        const float* __restrict__ gamma, const float* __restrict__ beta,
        float* __restrict__ out) {
    int row = blockIdx.x * 4 + (threadIdx.x >> 6);
    int tid = threadIdx.x & 63;
    int base = row * F_DIM;
    float x0 = a[base + tid], x1 = a[base + 64 + tid];
    if (resid) { x0 += resid[base + tid]; x1 += resid[base + 64 + tid]; }
    float s = x0 + x1;
#pragma unroll
    for (int o = 32; o > 0; o >>= 1) s += __shfl_xor(s, o);
    float mu = s * (1.f / 128.f);
    float d0 = x0 - mu, d1 = x1 - mu;
    float v = d0 * d0 + d1 * d1;
#pragma unroll
    for (int o = 32; o > 0; o >>= 1) v += __shfl_xor(v, o);
    float inv = rsqrtf(v * (1.f / 128.f) + 1e-5f);
    out[base + tid]      = d0 * inv * gamma[tid] + beta[tid];
    out[base + 64 + tid] = d1 * inv * gamma[64 + tid] + beta[64 + tid];
}

// fused LN2 + LNF: enc = LN(LN(a+resid; g2,b2); gf,bf) — x2 never materialized
__global__ __launch_bounds__(256) void ln2_lnf_kernel(
        const float* __restrict__ a, const float* __restrict__ resid,
        const float* __restrict__ g2, const float* __restrict__ b2,
        const float* __restrict__ gf, const float* __restrict__ bfp,
        float* __restrict__ out) {
    int row = blockIdx.x * 4 + (threadIdx.x >> 6);
    int tid = threadIdx.x & 63;
    int base = row * F_DIM;
    float x0 = a[base + tid] + resid[base + tid];
    float x1 = a[base + 64 + tid] + resid[base + 64 + tid];
    float s = x0 + x1;
#pragma unroll
    for (int o = 32; o > 0; o >>= 1) s += __shfl_xor(s, o);
    float mu = s * (1.f / 128.f);
    float d0 = x0 - mu, d1 = x1 - mu;
    float v = d0 * d0 + d1 * d1;
#pragma unroll
    for (int o = 32; o > 0; o >>= 1) v += __shfl_xor(v, o);
    float inv = rsqrtf(v * (1.f / 128.f) + 1e-5f);
    float y0 = d0 * inv * g2[tid] + b2[tid];
    float y1 = d1 * inv * g2[64 + tid] + b2[64 + tid];
    s = y0 + y1;
#pragma unroll
    for (int o = 32; o > 0; o >>= 1) s += __shfl_xor(s, o);
    mu = s * (1.f / 128.f);
    d0 = y0 - mu; d1 = y1 - mu;
    v = d0 * d0 + d1 * d1;
#pragma unroll
    for (int o = 32; o > 0; o >>= 1) v += __shfl_xor(v, o);
    inv = rsqrtf(v * (1.f / 128.f) + 1e-5f);
    out[base + tid]      = d0 * inv * gf[tid] + bfp[tid];
    out[base + 64 + tid] = d1 * inv * gf[64 + tid] + bfp[64 + tid];
}

// ---------------------------------------------------------------- 64x64 bf16 MFMA GEMM
template <bool TB, bool RELU, bool SPLITK, bool ABF16>
__global__ __launch_bounds__(256) void mfma_gemm(const void* __restrict__ Aptr,
                                                 const float* __restrict__ B,
                                                 const float* __restrict__ bias,
                                                 float* __restrict__ C,
                                                 int M, int K, int P, int Kc) {
    __shared__ short As[64][40];
    __shared__ short Bs[64][40];
    int tid = threadIdx.x;
    int p0 = blockIdx.x * 64, row0 = blockIdx.y * 64;
    int k_begin = SPLITK ? blockIdx.z * Kc : 0;
    int k_end   = SPLITK ? k_begin + Kc : K;
    int lane = tid & 63, w = tid >> 6, col = lane & 15, quad = lane >> 4;
    f32x4 acc[4];
#pragma unroll
    for (int j = 0; j < 4; ++j) acc[j] = (f32x4){0.f, 0.f, 0.f, 0.f};

    for (int k0 = k_begin; k0 < k_end; k0 += 32) {
        if (ABF16) {
            const short* A = (const short*)Aptr;
            int r = tid >> 2, c8 = (tid & 3) * 8;
            *(int4*)&As[r][c8] = *(const int4*)(A + (size_t)(row0 + r) * K + k0 + c8);
        } else {
            const float* A = (const float*)Aptr;
#pragma unroll
            for (int i = 0; i < 2; ++i) {
                int idx = tid * 2 + i;
                int r = idx >> 3, c4 = (idx & 7) << 2;
                const float4 f4 = *(const float4*)(A + (size_t)(row0 + r) * K + k0 + c4);
                union { __hip_bfloat162 h2[2]; short4 s4; } u;
                u.h2[0] = __float22bfloat162_rn(make_float2(f4.x, f4.y));
                u.h2[1] = __float22bfloat162_rn(make_float2(f4.z, f4.w));
                *(short4*)&As[r][c4] = u.s4;
            }
        }
        if (TB) {
#pragma unroll
            for (int i = 0; i < 2; ++i) {
                int idx = tid * 2 + i;
                int r = idx >> 3, c4 = (idx & 7) << 2;
                const float4 f4 = *(const float4*)(B + (size_t)(p0 + r) * K + k0 + c4);
                union { __hip_bfloat162 h2[2]; short4 s4; } u;
                u.h2[0] = __float22bfloat162_rn(make_float2(f4.x, f4.y));
                u.h2[1] = __float22bfloat162_rn(make_float2(f4.z, f4.w));
                *(short4*)&Bs[r][c4] = u.s4;
            }
        } else {
#pragma unroll
            for (int i = 0; i < 2; ++i) {
                int idx = tid * 2 + i;
                int kk = idx >> 4, c4 = (idx & 15) << 2;
                const float4 f4 = *(const float4*)(B + (size_t)(k0 + kk) * P + p0 + c4);
                Bs[c4 + 0][kk] = f2bf(f4.x);
                Bs[c4 + 1][kk] = f2bf(f4.y);
                Bs[c4 + 2][kk] = f2bf(f4.z);
                Bs[c4 + 3][kk] = f2bf(f4.w);
            }
        }
        __syncthreads();
        bf16x8 af = *(const bf16x8*)&As[w * 16 + col][quad * 8];
#pragma unroll
        for (int j = 0; j < 4; ++j) {
            bf16x8 bv = *(const bf16x8*)&Bs[j * 16 + col][quad * 8];
            acc[j] = __builtin_amdgcn_mfma_f32_16x16x32_bf16(af, bv, acc[j], 0, 0, 0);
        }
        __syncthreads();
    }
    size_t zoff = SPLITK ? (size_t)blockIdx.z * M * P : 0;
#pragma unroll
    for (int j = 0; j < 4; ++j) {
        int cg_ = p0 + j * 16 + col;
        float bvv = (!SPLITK && bias) ? bias[cg_] : 0.f;
#pragma unroll
        for (int r = 0; r < 4; ++r) {
            int rg = row0 + w * 16 + quad * 4 + r;
            float v = acc[j][r] + bvv;
            if (!SPLITK && RELU) v = fmaxf(v, 0.f);
            C[zoff + (size_t)rg * P + cg_] = v;
        }
    }
}

// ---------------------------------------------------------------- launch
extern "C" void kernel_launch(void* const* d_in, const int* in_sizes, int n_in,
                              void* d_out, int out_size, void* d_ws, size_t ws_size,
                              hipStream_t stream) {
    const int*   A_cols     = (const int*)d_in[1];
    const float* A_vals     = (const float*)d_in[2];
    const float* X          = (const float*)d_in[3];
    const float* W_gcn      = (const float*)d_in[4];
    const float* W_ih       = (const float*)d_in[5];
    const float* W_hh       = (const float*)d_in[6];
    const float* b_ih       = (const float*)d_in[7];
    const float* b_hh       = (const float*)d_in[8];
    const float* in_proj_w  = (const float*)d_in[9];
    const float* in_proj_b  = (const float*)d_in[10];
    const float* out_proj_w = (const float*)d_in[11];
    const float* out_proj_b = (const float*)d_in[12];
    const float* ln1_g = (const float*)d_in[13];
    const float* ln1_b = (const float*)d_in[14];
    const float* ln2_g = (const float*)d_in[15];
    const float* ln2_b = (const float*)d_in[16];
    const float* lnf_g = (const float*)d_in[17];
    const float* lnf_b = (const float*)d_in[18];
    const float* ff1_w = (const float*)d_in[19];
    const float* ff1_b = (const float*)d_in[20];
    const float* ff2_w = (const float*)d_in[21];
    const float* ff2_b = (const float*)d_in[22];
    const float* fc1_w = (const float*)d_in[23];
    const float* fc1_b = (const float*)d_in[24];
    const float* fc2_w = (const float*)d_in[25];
    const float* fc2_b = (const float*)d_in[26];
    const float* fc3_w = (const float*)d_in[27];
    const float* fc3_b = (const float*)d_in[28];
    float* out = (float*)d_out;
    float* ws  = (float*)d_ws;

    const size_t o_Hm = 0;
    const size_t o_A  = o_Hm + 4194304;
    const size_t o_B  = o_A + 4194304;
    const size_t o_C  = o_B + 4194304;           // GI -> ff_hid(bf16)
    const size_t o_D  = o_C + 12582912;          // Qb/Kb/VTb/Vb bf16 -> head partials
    const size_t o_WT = o_D + 12582912;          // bf16 weights (scan)
    const size_t o_h  = o_WT + 49152;
    const size_t o_g  = o_h + 131072;
    const size_t o_h1 = o_g + 131072;
    const size_t o_h2 = o_h1 + 524288;

    float* Hm    = ws + o_Hm;
    float* bufA  = ws + o_A;
    short* Xs    = (short*)bufA;                 // X_s bf16 [N, TF] (dead after step 2)
    float* bufB  = ws + o_B;
    float* bufC  = ws + o_C;
    short* ffh   = (short*)bufC;                 // ff_hid bf16 [NT, 512]
    short* Qb    = (short*)(ws + o_D);
    short* Kb    = Qb + 4194304;
    short* VTb   = Kb + 4194304;
    short* Vb    = VTb + 4194304;
    float* partbuf = ws + o_D;                   // head partials (o_D dead after attn)
    unsigned short* WhhT_bf = (unsigned short*)(ws + o_WT);   // 49152 ushort
    unsigned short* Wg_bf   = WhhT_bf + 49152;                // 16384 ushort
    float* g0    = ws + o_g;
    float* h1    = ws + o_h1;
    float* h2    = ws + o_h2;
    float* g1    = h2;                           // alias: h2 dead during scan

    // 1. X_s = A_hat @ X -> Xs (bf16); c-slice-major dispatch for L2 locality
    spmm_wide<<<dim3(1024, 16), 256, 0, stream>>>(A_cols, A_vals, X, Xs);
    // 2. X_tilde = relu(X_s @ W_gcn) -> bufB  (bf16 A)
    mfma_gemm<false, true, false, true><<<dim3(2, 512), 256, 0, stream>>>(Xs, W_gcn, nullptr, bufB, NT, F_DIM, F_DIM, 0);
    // 3. GI = X_tilde @ W_ih^T + b_ih -> bufC  (128-tile)
    mfma_gemm128<false, false, false><<<dim3(3, 256), 256, 0, stream>>>(bufB, W_ih, b_ih, bufC, NT, F_DIM, F3);
    // 4. bf16 weight prep (scan)
    prep_weights<<<192, 256, 0, stream>>>(W_hh, W_gcn, WhhT_bf, Wg_bf);
    // 5. g(0), Hm[:,0]  (h0=0, GH0=0 algebraically)
    gates0_kernel<<<512, 256, 0, stream>>>(bufC, b_hh, g0, Hm);
    // 6. fused scan: one launch per step; h/GH stay on-chip (512 blocks = 2/CU)
    for (int s = 0; s < T_STEPS - 1; ++s) {
        const float* gi = (s & 1) ? g1 : g0;
        float*       go = (s & 1) ? g0 : g1;
        scan_step<<<512, 256, 0, stream>>>(A_cols, A_vals, gi, Wg_bf, WhhT_bf, b_hh, bufC, go, Hm, s + 1);
    }
    // 7. qkv projection (128-tile) -> Qb/Kb/Vb (all K-layout)
    qkv_gemm128<<<dim3(3, 256), 256, 0, stream>>>(Hm, in_proj_w, in_proj_b, Qb, Kb, Vb);
    // 7b. V transpose through LDS (coalesced both sides)
    vtrans<<<dim3(128, 32), 256, 0, stream>>>(Vb, VTb);
    // 8. MFMA attention -> ctx (bufA)
    attn_mfma<<<dim3(128, 16), 256, 0, stream>>>(Qb, Kb, VTb, bufA);
    // 9. attn_out = ctx @ out_proj_w^T + b -> bufB
    mfma_gemm<true, false, false, false><<<dim3(2, 512), 256, 0, stream>>>(bufA, out_proj_w, out_proj_b, bufB, NT, F_DIM, F_DIM, 0);
    // 10. x1 = LN(Hm + attn_out) -> bufA
    ln_kernel<<<NT / 4, 256, 0, stream>>>(Hm, bufB, ln1_g, ln1_b, bufA);
    // 11. ff_hid = relu(x1 @ ff1_w^T + b) -> ffh (bf16, 128-tile)
    mfma_gemm128<true, false, true><<<dim3(4, 256), 256, 0, stream>>>(bufA, ff1_w, ff1_b, ffh, NT, F_DIM, HID);
    // 12. ff_out = ff_hid @ ff2_w^T + b -> bufB  (64-tile, bf16 A, 1024 blocks)
    mfma_gemm<true, false, false, true><<<dim3(2, 512), 256, 0, stream>>>(ffh, ff2_w, ff2_b, bufB, NT, HID, F_DIM, 0);
    // 13+14. enc = LN(LN(x1 + ff_out)) -> bufA  (fused)
    ln2_lnf_kernel<<<NT / 4, 256, 0, stream>>>(bufA, bufB, ln2_g, ln2_b, lnf_g, lnf_b, bufA);
    // 15. h1 = relu(enc_flat @ fc1_w^T + b)  — split-K=4 partials + reduce
    mfma_gemm<true, false, true, false><<<dim3(8, 16, 4), 256, 0, stream>>>(bufA, fc1_w, nullptr, partbuf, N_NODES, TF, HID, 1024);
    reduce_bias<true><<<2048, 256, 0, stream>>>(partbuf, 4, 524288, fc1_b, HID, h1);
    // 16. h2 = relu(h1 @ fc2_w^T + b) — split-K=4 partials + reduce
    mfma_gemm<true, false, true, false><<<dim3(8, 16, 4), 256, 0, stream>>>(h1, fc2_w, nullptr, partbuf, N_NODES, HID, HID, 128);
    reduce_bias<true><<<2048, 256, 0, stream>>>(partbuf, 4, 524288, fc2_b, HID, h2);
    // 17. out = h2 @ fc3_w^T + b — split-K=8 partials + reduce
    mfma_gemm<true, false, true, false><<<dim3(1, 16, 8), 256, 0, stream>>>(h2, fc3_w, nullptr, partbuf, N_NODES, HID, OUT_DIM, 64);
    reduce_bias<false><<<256, 256, 0, stream>>>(partbuf, 8, 65536, fc3_b, OUT_DIM, out);
}

// Round 15
// 726.044 us; speedup vs baseline: 1.1783x; 1.0231x over previous
//
#include <hip/hip_runtime.h>
#include <hip/hip_bf16.h>
#include <math.h>

#define N_NODES 1024
#define T_STEPS 32
#define F_DIM   128
#define H_HEADS 4
#define D_HEAD  32
#define DEG     32
#define HID     512
#define OUT_DIM 64
#define TF      (T_STEPS * F_DIM)   // 4096
#define NT      (N_NODES * T_STEPS) // 32768
#define F3      (3 * F_DIM)         // 384

typedef __attribute__((ext_vector_type(8))) __bf16 bf16x8;
typedef __attribute__((ext_vector_type(4))) float  f32x4;

// float -> bf16 bits, round-to-nearest-even (scalar fallback)
__device__ __forceinline__ short f2bf(float x) {
    union { float f; unsigned u; } v; v.f = x;
    unsigned r = (v.u + 0x7FFFu + ((v.u >> 16) & 1u)) >> 16;
    return (short)r;
}
__device__ __forceinline__ float bf2f(unsigned short b) {
    union { unsigned u; float f; } v; v.u = ((unsigned)b) << 16; return v.f;
}

// ---------------------------------------------------------------- utilities
// one-time: W_hh [384,128] -> bf16 WhhT [128,384]; W_gcn [128,128] -> bf16 (same layout)
__global__ void prep_weights(const float* __restrict__ W_hh, const float* __restrict__ W_gcn,
                             unsigned short* __restrict__ WhhT_bf,
                             unsigned short* __restrict__ Wg_bf) {
    int idx = blockIdx.x * 256 + threadIdx.x;
    if (idx < F3 * F_DIM) {
        int j = idx / F_DIM;   // 0..383
        int k = idx % F_DIM;   // 0..127
        WhhT_bf[k * F3 + j] = (unsigned short)f2bf(W_hh[idx]);
    }
    if (idx < F_DIM * F_DIM) {
        Wg_bf[idx] = (unsigned short)f2bf(W_gcn[idx]);
    }
}

// split-K partial reduction + bias (+relu)
template <bool RELU>
__global__ void reduce_bias(const float* __restrict__ part, int nz, int MP,
                            const float* __restrict__ bias, int P,
                            float* __restrict__ C) {
    int i = blockIdx.x * 256 + threadIdx.x;
    if (i < MP) {
        float v = bias[i & (P - 1)];
        for (int z = 0; z < nz; ++z) v += part[(size_t)z * MP + i];
        if (RELU) v = fmaxf(v, 0.f);
        C[i] = v;
    }
}

// ---------------------------------------------------------------- SpMM (wide): Y[n, :] = sum_e vals * X[cols[e], :]
__global__ void spmm_wide(const int* __restrict__ cols, const float* __restrict__ vals,
                          const float* __restrict__ X, short* __restrict__ Y) {
    int n = blockIdx.x;
    int c = blockIdx.y * 256 + threadIdx.x;
    const int*   ce = cols + n * DEG;
    const float* ve = vals + n * DEG;
    float acc = 0.f;
#pragma unroll
    for (int e = 0; e < DEG; ++e) acc += ve[e] * X[(size_t)ce[e] * TF + c];
    Y[(size_t)n * TF + c] = f2bf(acc);
}

// ---------------------------------------------------------------- t=0 gates: h=0, GH=0 algebraically; pe(t=0)=sin(0)=0
__global__ __launch_bounds__(256) void gates0_kernel(
        const float* __restrict__ GI, const float* __restrict__ b_hh,
        float* __restrict__ g_out, float* __restrict__ Hm) {
    int idx = blockIdx.x * 256 + threadIdx.x;   // over N*F
    int n = idx >> 7, f = idx & 127;
    size_t gib = (size_t)n * T_STEPS * F3;
    float rr = 1.f / (1.f + expf(-(GI[gib + f] + b_hh[f])));
    float zz = 1.f / (1.f + expf(-(GI[gib + 128 + f] + b_hh[128 + f])));
    float nn = tanhf(GI[gib + 256 + f] + rr * b_hh[256 + f]);
    float g  = (1.f - zz) * nn;
    g_out[idx] = g;
    Hm[(size_t)n * T_STEPS * F_DIM + f] = g;    // pe = 0 at t=0
}

// ---------------------------------------------------------------- fully fused scan step, 2 nodes/block (512 blocks)
// Weight reads are scalar-per-thread but wave-coalesced (64 lanes x 2B = one line).
__global__ __launch_bounds__(256) void scan_step(
        const int* __restrict__ cols, const float* __restrict__ vals,
        const float* __restrict__ g_in, const unsigned short* __restrict__ Wg_bf,
        const unsigned short* __restrict__ WhhT_bf, const float* __restrict__ b_hh,
        const float* __restrict__ GI, float* __restrict__ g_out,
        float* __restrict__ Hm, int t_next) {
    __shared__ float sp[2][F_DIM];
    __shared__ float hsn[2][F_DIM];
    __shared__ float part[2][F_DIM][8];    // 6 used, +2 pad
    __shared__ float gpart[2][2][F_DIM];
    int tid = threadIdx.x;
    int n0 = blockIdx.x * 2;
    int f = tid & 127, half = tid >> 7;
    // ---- SpMM: edges split across halves
    float b0 = 0.f, b1 = 0.f;
    int eb = half * 16;
#pragma unroll
    for (int e = 0; e < 16; ++e) {
        int i0 = n0 * DEG + eb + e;
        int i1 = (n0 + 1) * DEG + eb + e;
        b0 += vals[i0] * g_in[cols[i0] * F_DIM + f];
        b1 += vals[i1] * g_in[cols[i1] * F_DIM + f];
    }
    gpart[half][0][f] = b0; gpart[half][1][f] = b1;
    __syncthreads();
    sp[half][f] = gpart[0][half][f] + gpart[1][half][f];   // half doubles as node idx
    __syncthreads();
    // ---- GCN: k range split across halves (bf16 weights, coalesced)
    float c0 = 0.f, c1 = 0.f;
    int kb = half * 64;
#pragma unroll 4
    for (int k = 0; k < 64; ++k) {
        int kk = kb + k;
        float w = bf2f(Wg_bf[kk * F_DIM + f]);
        c0 += sp[0][kk] * w; c1 += sp[1][kk] * w;
    }
    gpart[half][0][f] = c0; gpart[half][1][f] = c1;
    __syncthreads();
    hsn[half][f] = fmaxf(gpart[0][half][f] + gpart[1][half][f], 0.f);
    __syncthreads();
    // ---- GH = h_new @ W_hh^T : k split, 2 nodes x 3 gates (bf16 weights, coalesced)
    float a[6] = {0.f, 0.f, 0.f, 0.f, 0.f, 0.f};
#pragma unroll 2
    for (int k = 0; k < 64; ++k) {
        int kk = kb + k;
        const unsigned short* w = WhhT_bf + kk * F3;
        float wr = bf2f(w[f]), wz = bf2f(w[128 + f]), wn = bf2f(w[256 + f]);
        float h0 = hsn[0][kk], h1 = hsn[1][kk];
        a[0] += h0 * wr; a[1] += h0 * wz; a[2] += h0 * wn;
        a[3] += h1 * wr; a[4] += h1 * wz; a[5] += h1 * wn;
    }
#pragma unroll
    for (int i = 0; i < 6; ++i) part[half][f][i] = a[i];
    __syncthreads();
    // ---- gates for own node (node = n0+half), all inputs local
    {
        int node = n0 + half;
        float ghr = part[0][f][half * 3 + 0] + part[1][f][half * 3 + 0] + b_hh[f];
        float ghz = part[0][f][half * 3 + 1] + part[1][f][half * 3 + 1] + b_hh[128 + f];
        float ghn = part[0][f][half * 3 + 2] + part[1][f][half * 3 + 2] + b_hh[256 + f];
        size_t gib = ((size_t)node * T_STEPS + t_next) * F3;
        float hv = hsn[half][f];
        float rr = 1.f / (1.f + expf(-(GI[gib + f] + ghr)));
        float zz = 1.f / (1.f + expf(-(GI[gib + 128 + f] + ghz)));
        float nn = tanhf(GI[gib + 256 + f] + rr * ghn);
        float g  = (1.f - zz) * nn + zz * hv;
        g_out[node * F_DIM + f] = g;
        float inv = __expf(-(float)node * (9.210340371976184f / 64.0f));
        float ang = (float)t_next * inv;
        float pe  = ((t_next & 1) == 0) ? sinf(ang) : cosf(ang);
        Hm[((size_t)node * T_STEPS + t_next) * F_DIM + f] = g + pe;
    }
}

// ================================================================ 128x128-tile bf16 MFMA GEMM core (B is [P,K])
template <bool RELU, bool ABF16, bool BF16OUT>
__global__ __launch_bounds__(256) void mfma_gemm128(const void* __restrict__ Aptr,
                                                    const float* __restrict__ B,
                                                    const float* __restrict__ bias,
                                                    void* __restrict__ Cptr,
                                                    int M, int K, int P) {
    __shared__ short As[128][40];
    __shared__ short Bs[128][40];
    int tid = threadIdx.x;
    int p0 = blockIdx.x * 128, row0 = blockIdx.y * 128;
    int lane = tid & 63, w = tid >> 6, col = lane & 15, quad = lane >> 4;
    int qr = w >> 1, qc = w & 1;
    f32x4 acc[4][4];
#pragma unroll
    for (int j = 0; j < 4; ++j)
#pragma unroll
        for (int jj = 0; jj < 4; ++jj) acc[j][jj] = (f32x4){0.f, 0.f, 0.f, 0.f};

    for (int k0 = 0; k0 < K; k0 += 32) {
        if (ABF16) {
            const short* A = (const short*)Aptr;
#pragma unroll
            for (int i = 0; i < 2; ++i) {
                int idx = tid * 2 + i;              // 512 chunks of 8 shorts
                int r = idx >> 2, c8 = (idx & 3) * 8;
                *(int4*)&As[r][c8] = *(const int4*)(A + (size_t)(row0 + r) * K + k0 + c8);
            }
        } else {
            const float* A = (const float*)Aptr;
#pragma unroll
            for (int i = 0; i < 4; ++i) {
                int idx = tid * 4 + i;
                int r = idx >> 3, c4 = (idx & 7) << 2;
                const float4 f4 = *(const float4*)(A + (size_t)(row0 + r) * K + k0 + c4);
                union { __hip_bfloat162 h2[2]; short4 s4; } u;
                u.h2[0] = __float22bfloat162_rn(make_float2(f4.x, f4.y));
                u.h2[1] = __float22bfloat162_rn(make_float2(f4.z, f4.w));
                *(short4*)&As[r][c4] = u.s4;
            }
        }
#pragma unroll
        for (int i = 0; i < 4; ++i) {
            int idx = tid * 4 + i;
            int r = idx >> 3, c4 = (idx & 7) << 2;
            const float4 f4 = *(const float4*)(B + (size_t)(p0 + r) * K + k0 + c4);
            union { __hip_bfloat162 h2[2]; short4 s4; } u;
            u.h2[0] = __float22bfloat162_rn(make_float2(f4.x, f4.y));
            u.h2[1] = __float22bfloat162_rn(make_float2(f4.z, f4.w));
            *(short4*)&Bs[r][c4] = u.s4;
        }
        __syncthreads();
        bf16x8 af[4], bfr[4];
#pragma unroll
        for (int j = 0; j < 4; ++j) af[j]  = *(const bf16x8*)&As[qr * 64 + j * 16 + col][quad * 8];
#pragma unroll
        for (int j = 0; j < 4; ++j) bfr[j] = *(const bf16x8*)&Bs[qc * 64 + j * 16 + col][quad * 8];
#pragma unroll
        for (int j = 0; j < 4; ++j)
#pragma unroll
            for (int jj = 0; jj < 4; ++jj)
                acc[j][jj] = __builtin_amdgcn_mfma_f32_16x16x32_bf16(af[j], bfr[jj], acc[j][jj], 0, 0, 0);
        __syncthreads();
    }
#pragma unroll
    for (int j = 0; j < 4; ++j) {
#pragma unroll
        for (int jj = 0; jj < 4; ++jj) {
            int cg = p0 + qc * 64 + jj * 16 + col;
            float bvv = bias ? bias[cg] : 0.f;
#pragma unroll
            for (int r = 0; r < 4; ++r) {
                int rg = row0 + qr * 64 + j * 16 + quad * 4 + r;
                float v = acc[j][jj][r] + bvv;
                if (RELU) v = fmaxf(v, 0.f);
                if (BF16OUT) ((short*)Cptr)[(size_t)rg * P + cg] = f2bf(v);
                else         ((float*)Cptr)[(size_t)rg * P + cg] = v;
            }
        }
    }
}

// qkv variant: same 128x128 core, epilogue writes bf16 Qb/Kb/Vb all in [T*H,N,D]
// Q scaled by 1/sqrt(D) * log2(e) so attention can use exp2 directly.
__global__ __launch_bounds__(256) void qkv_gemm128(const float* __restrict__ A,
                                                   const float* __restrict__ B,
                                                   const float* __restrict__ bias,
                                                   short* __restrict__ Qb,
                                                   short* __restrict__ Kb,
                                                   short* __restrict__ Vb) {
    __shared__ short As[128][40];
    __shared__ short Bs[128][40];
    int tid = threadIdx.x;
    int p0 = blockIdx.x * 128, row0 = blockIdx.y * 128;
    int lane = tid & 63, w = tid >> 6, col = lane & 15, quad = lane >> 4;
    int qr = w >> 1, qc = w & 1;
    const int K = F_DIM;
    f32x4 acc[4][4];
#pragma unroll
    for (int j = 0; j < 4; ++j)
#pragma unroll
        for (int jj = 0; jj < 4; ++jj) acc[j][jj] = (f32x4){0.f, 0.f, 0.f, 0.f};

    for (int k0 = 0; k0 < K; k0 += 32) {
#pragma unroll
        for (int i = 0; i < 4; ++i) {
            int idx = tid * 4 + i;
            int r = idx >> 3, c4 = (idx & 7) << 2;
            const float4 f4 = *(const float4*)(A + (size_t)(row0 + r) * K + k0 + c4);
            union { __hip_bfloat162 h2[2]; short4 s4; } u;
            u.h2[0] = __float22bfloat162_rn(make_float2(f4.x, f4.y));
            u.h2[1] = __float22bfloat162_rn(make_float2(f4.z, f4.w));
            *(short4*)&As[r][c4] = u.s4;
        }
#pragma unroll
        for (int i = 0; i < 4; ++i) {
            int idx = tid * 4 + i;
            int r = idx >> 3, c4 = (idx & 7) << 2;
            const float4 f4 = *(const float4*)(B + (size_t)(p0 + r) * K + k0 + c4);
            union { __hip_bfloat162 h2[2]; short4 s4; } u;
            u.h2[0] = __float22bfloat162_rn(make_float2(f4.x, f4.y));
            u.h2[1] = __float22bfloat162_rn(make_float2(f4.z, f4.w));
            *(short4*)&Bs[r][c4] = u.s4;
        }
        __syncthreads();
        bf16x8 af[4], bfr[4];
#pragma unroll
        for (int j = 0; j < 4; ++j) af[j]  = *(const bf16x8*)&As[qr * 64 + j * 16 + col][quad * 8];
#pragma unroll
        for (int j = 0; j < 4; ++j) bfr[j] = *(const bf16x8*)&Bs[qc * 64 + j * 16 + col][quad * 8];
#pragma unroll
        for (int j = 0; j < 4; ++j)
#pragma unroll
            for (int jj = 0; jj < 4; ++jj)
                acc[j][jj] = __builtin_amdgcn_mfma_f32_16x16x32_bf16(af[j], bfr[jj], acc[j][jj], 0, 0, 0);
        __syncthreads();
    }
#pragma unroll
    for (int j = 0; j < 4; ++j) {
#pragma unroll
        for (int jj = 0; jj < 4; ++jj) {
            int cg = p0 + qc * 64 + jj * 16 + col;
            int which = cg >> 7, f = cg & 127;
            int hh = f >> 5, d = f & 31;
            float bv = bias[cg];
#pragma unroll
            for (int r = 0; r < 4; ++r) {
                int rg = row0 + qr * 64 + j * 16 + quad * 4 + r;
                int n = rg >> 5, t = rg & 31;
                int th = t * H_HEADS + hh;
                size_t dst = ((size_t)th * N_NODES + n) * D_HEAD + d;
                float v = acc[j][jj][r] + bv;
                if (which == 0)      Qb[dst] = f2bf(v * (0.17677669529663687f * 1.4426950408889634f));
                else if (which == 1) Kb[dst] = f2bf(v);
                else                 Vb[dst] = f2bf(v);
            }
        }
    }
}

// ---------------------------------------------------------------- V transpose: Vb [T*H,N,D] -> VTb [T*H,D,N], coalesced
__global__ __launch_bounds__(256) void vtrans(const short* __restrict__ Vb,
                                              short* __restrict__ VTb) {
    __shared__ short tile[32][36];
    int th = blockIdx.x;
    int n0 = blockIdx.y * 32;
    int tid = threadIdx.x;
    {
        int n_i = tid >> 3, d0 = (tid & 7) * 4;
        *(short4*)&tile[n_i][d0] =
            *(const short4*)(Vb + ((size_t)th * N_NODES + n0 + n_i) * D_HEAD + d0);
    }
    __syncthreads();
    {
        int d = tid >> 3, m0 = (tid & 7) * 4;
        short4 o;
        o.x = tile[m0 + 0][d]; o.y = tile[m0 + 1][d];
        o.z = tile[m0 + 2][d]; o.w = tile[m0 + 3][d];
        *(short4*)(VTb + ((size_t)th * D_HEAD + d) * N_NODES + n0 + m0) = o;
    }
}

// ---------------------------------------------------------------- MFMA flash attention, 4 waves/block sharing K/V via LDS
// Q pre-scaled by log2(e): weights are exp2(s) via the raw v_exp_f32 intrinsic.
__global__ __launch_bounds__(256) void attn_mfma(const short* __restrict__ Qb,
                                                 const short* __restrict__ Kb,
                                                 const short* __restrict__ VTb,
                                                 float* __restrict__ ctx) {
    int th = blockIdx.x;
    int t = th >> 2, hh = th & 3;
    int q0 = blockIdx.y * 64;
    int tid = threadIdx.x;
    int w = tid >> 6, lane = tid & 63;
    int col = lane & 15, quad = lane >> 4;
    __shared__ short    Ks[32][40];       // row stride 80B (16B-aligned)
    __shared__ short    Vs[32][40];
    __shared__ unsigned Ps[4][16][20];    // dwords; row stride 80B

    bf16x8 qf = *(const bf16x8*)(Qb + ((size_t)th * N_NODES + q0 + w * 16 + col) * D_HEAD + quad * 8);
    const short* Kbase = Kb  + (size_t)th * (N_NODES * D_HEAD);
    const short* Vbase = VTb + (size_t)th * (D_HEAD * N_NODES);

    int lrw = tid >> 3;                    // staging row 0..31
    int lc  = (tid & 7) * 4;               // staging col (shorts)
    int kperm = ((lrw & 15) << 1) | (lrw >> 4);   // rows 0..15 -> even m, 16..31 -> odd m

    f32x4 o0 = {0.f, 0.f, 0.f, 0.f}, o1 = {0.f, 0.f, 0.f, 0.f};
    float l0 = 0.f, l1 = 0.f, l2 = 0.f, l3 = 0.f;
    const f32x4 zc = {0.f, 0.f, 0.f, 0.f};

    for (int mt = 0; mt < 32; ++mt) {
        int m0 = mt * 32;
        __syncthreads();   // WAR: previous iteration's Ks/Vs reads done
        *(short4*)&Ks[lrw][lc] = *(const short4*)(Kbase + (size_t)(m0 + kperm) * D_HEAD + lc);
        *(short4*)&Vs[lrw][lc] = *(const short4*)(Vbase + (size_t)lrw * N_NODES + m0 + lc);
        __syncthreads();   // tiles visible
        bf16x8 k0 = *(const bf16x8*)&Ks[col][quad * 8];        // K[m0+2col]
        bf16x8 k1 = *(const bf16x8*)&Ks[col + 16][quad * 8];   // K[m0+2col+1]
        f32x4 s0 = __builtin_amdgcn_mfma_f32_16x16x32_bf16(qf, k0, zc, 0, 0, 0);
        f32x4 s1 = __builtin_amdgcn_mfma_f32_16x16x32_bf16(qf, k1, zc, 0, 0, 0);
        float ps[4][2];
#pragma unroll
        for (int r = 0; r < 4; ++r) {
            ps[r][0] = __builtin_amdgcn_exp2f(s0[r]);
            ps[r][1] = __builtin_amdgcn_exp2f(s1[r]);
            union { __hip_bfloat162 h; unsigned u; } u;
            u.h = __float22bfloat162_rn(make_float2(ps[r][0], ps[r][1]));
            Ps[w][quad * 4 + r][col] = u.u;   // natural m order
        }
        l0 += ps[0][0] + ps[0][1]; l1 += ps[1][0] + ps[1][1];
        l2 += ps[2][0] + ps[2][1]; l3 += ps[3][0] + ps[3][1];
        __builtin_amdgcn_s_waitcnt(0xC07F);   // lgkmcnt(0): own Ps writes committed
        bf16x8 pf = *(const bf16x8*)&Ps[w][col][quad * 4];     // A-frag, natural m order
        bf16x8 v0 = *(const bf16x8*)&Vs[col][quad * 8];        // V^T[d=col][m0+quad*8..]
        bf16x8 v1 = *(const bf16x8*)&Vs[col + 16][quad * 8];
        o0 = __builtin_amdgcn_mfma_f32_16x16x32_bf16(pf, v0, o0, 0, 0, 0);
        o1 = __builtin_amdgcn_mfma_f32_16x16x32_bf16(pf, v1, o1, 0, 0, 0);
    }
    float lr[4] = {l0, l1, l2, l3};
#pragma unroll
    for (int r = 0; r < 4; ++r) {
        float s = lr[r];
        s += __shfl_xor(s, 1); s += __shfl_xor(s, 2);
        s += __shfl_xor(s, 4); s += __shfl_xor(s, 8);
        lr[r] = 1.f / s;
    }
#pragma unroll
    for (int r = 0; r < 4; ++r) {
        int n = q0 + w * 16 + quad * 4 + r;
        size_t base = ((size_t)n * T_STEPS + t) * F_DIM + hh * D_HEAD;
        ctx[base + col]      = o0[r] * lr[r];
        ctx[base + 16 + col] = o1[r] * lr[r];
    }
}

// ---------------------------------------------------------------- LayerNorm over F=128, 4 rows/block, optional residual
__global__ __launch_bounds__(256) void ln_kernel(
        const float* __restrict__ a, const float* __restrict__ resid,
        const float* __restrict__ gamma, const float* __restrict__ beta,
        float* __restrict__ out) {
    int row = blockIdx.x * 4 + (threadIdx.x >> 6);
    int tid = threadIdx.x & 63;
    int base = row * F_DIM;
    float x0 = a[base + tid], x1 = a[base + 64 + tid];
    if (resid) { x0 += resid[base + tid]; x1 += resid[base + 64 + tid]; }
    float s = x0 + x1;
#pragma unroll
    for (int o = 32; o > 0; o >>= 1) s += __shfl_xor(s, o);
    float mu = s * (1.f / 128.f);
    float d0 = x0 - mu, d1 = x1 - mu;
    float v = d0 * d0 + d1 * d1;
#pragma unroll
    for (int o = 32; o > 0; o >>= 1) v += __shfl_xor(v, o);
    float inv = rsqrtf(v * (1.f / 128.f) + 1e-5f);
    out[base + tid]      = d0 * inv * gamma[tid] + beta[tid];
    out[base + 64 + tid] = d1 * inv * gamma[64 + tid] + beta[64 + tid];
}

// fused LN2 + LNF: enc = LN(LN(a+resid; g2,b2); gf,bf) — x2 never materialized
__global__ __launch_bounds__(256) void ln2_lnf_kernel(
        const float* __restrict__ a, const float* __restrict__ resid,
        const float* __restrict__ g2, const float* __restrict__ b2,
        const float* __restrict__ gf, const float* __restrict__ bfp,
        float* __restrict__ out) {
    int row = blockIdx.x * 4 + (threadIdx.x >> 6);
    int tid = threadIdx.x & 63;
    int base = row * F_DIM;
    float x0 = a[base + tid] + resid[base + tid];
    float x1 = a[base + 64 + tid] + resid[base + 64 + tid];
    float s = x0 + x1;
#pragma unroll
    for (int o = 32; o > 0; o >>= 1) s += __shfl_xor(s, o);
    float mu = s * (1.f / 128.f);
    float d0 = x0 - mu, d1 = x1 - mu;
    float v = d0 * d0 + d1 * d1;
#pragma unroll
    for (int o = 32; o > 0; o >>= 1) v += __shfl_xor(v, o);
    float inv = rsqrtf(v * (1.f / 128.f) + 1e-5f);
    float y0 = d0 * inv * g2[tid] + b2[tid];
    float y1 = d1 * inv * g2[64 + tid] + b2[64 + tid];
    s = y0 + y1;
#pragma unroll
    for (int o = 32; o > 0; o >>= 1) s += __shfl_xor(s, o);
    mu = s * (1.f / 128.f);
    d0 = y0 - mu; d1 = y1 - mu;
    v = d0 * d0 + d1 * d1;
#pragma unroll
    for (int o = 32; o > 0; o >>= 1) v += __shfl_xor(v, o);
    inv = rsqrtf(v * (1.f / 128.f) + 1e-5f);
    out[base + tid]      = d0 * inv * gf[tid] + bfp[tid];
    out[base + 64 + tid] = d1 * inv * gf[64 + tid] + bfp[64 + tid];
}

// ---------------------------------------------------------------- 64x64 bf16 MFMA GEMM
template <bool TB, bool RELU, bool SPLITK, bool ABF16>
__global__ __launch_bounds__(256) void mfma_gemm(const void* __restrict__ Aptr,
                                                 const float* __restrict__ B,
                                                 const float* __restrict__ bias,
                                                 float* __restrict__ C,
                                                 int M, int K, int P, int Kc) {
    __shared__ short As[64][40];
    __shared__ short Bs[64][40];
    int tid = threadIdx.x;
    int p0 = blockIdx.x * 64, row0 = blockIdx.y * 64;
    int k_begin = SPLITK ? blockIdx.z * Kc : 0;
    int k_end   = SPLITK ? k_begin + Kc : K;
    int lane = tid & 63, w = tid >> 6, col = lane & 15, quad = lane >> 4;
    f32x4 acc[4];
#pragma unroll
    for (int j = 0; j < 4; ++j) acc[j] = (f32x4){0.f, 0.f, 0.f, 0.f};

    for (int k0 = k_begin; k0 < k_end; k0 += 32) {
        if (ABF16) {
            const short* A = (const short*)Aptr;
            int r = tid >> 2, c8 = (tid & 3) * 8;
            *(int4*)&As[r][c8] = *(const int4*)(A + (size_t)(row0 + r) * K + k0 + c8);
        } else {
            const float* A = (const float*)Aptr;
#pragma unroll
            for (int i = 0; i < 2; ++i) {
                int idx = tid * 2 + i;
                int r = idx >> 3, c4 = (idx & 7) << 2;
                const float4 f4 = *(const float4*)(A + (size_t)(row0 + r) * K + k0 + c4);
                union { __hip_bfloat162 h2[2]; short4 s4; } u;
                u.h2[0] = __float22bfloat162_rn(make_float2(f4.x, f4.y));
                u.h2[1] = __float22bfloat162_rn(make_float2(f4.z, f4.w));
                *(short4*)&As[r][c4] = u.s4;
            }
        }
        if (TB) {
#pragma unroll
            for (int i = 0; i < 2; ++i) {
                int idx = tid * 2 + i;
                int r = idx >> 3, c4 = (idx & 7) << 2;
                const float4 f4 = *(const float4*)(B + (size_t)(p0 + r) * K + k0 + c4);
                union { __hip_bfloat162 h2[2]; short4 s4; } u;
                u.h2[0] = __float22bfloat162_rn(make_float2(f4.x, f4.y));
                u.h2[1] = __float22bfloat162_rn(make_float2(f4.z, f4.w));
                *(short4*)&Bs[r][c4] = u.s4;
            }
        } else {
#pragma unroll
            for (int i = 0; i < 2; ++i) {
                int idx = tid * 2 + i;
                int kk = idx >> 4, c4 = (idx & 15) << 2;
                const float4 f4 = *(const float4*)(B + (size_t)(k0 + kk) * P + p0 + c4);
                Bs[c4 + 0][kk] = f2bf(f4.x);
                Bs[c4 + 1][kk] = f2bf(f4.y);
                Bs[c4 + 2][kk] = f2bf(f4.z);
                Bs[c4 + 3][kk] = f2bf(f4.w);
            }
        }
        __syncthreads();
        bf16x8 af = *(const bf16x8*)&As[w * 16 + col][quad * 8];
#pragma unroll
        for (int j = 0; j < 4; ++j) {
            bf16x8 bv = *(const bf16x8*)&Bs[j * 16 + col][quad * 8];
            acc[j] = __builtin_amdgcn_mfma_f32_16x16x32_bf16(af, bv, acc[j], 0, 0, 0);
        }
        __syncthreads();
    }
    size_t zoff = SPLITK ? (size_t)blockIdx.z * M * P : 0;
#pragma unroll
    for (int j = 0; j < 4; ++j) {
        int cg_ = p0 + j * 16 + col;
        float bvv = (!SPLITK && bias) ? bias[cg_] : 0.f;
#pragma unroll
        for (int r = 0; r < 4; ++r) {
            int rg = row0 + w * 16 + quad * 4 + r;
            float v = acc[j][r] + bvv;
            if (!SPLITK && RELU) v = fmaxf(v, 0.f);
            C[zoff + (size_t)rg * P + cg_] = v;
        }
    }
}

// ---------------------------------------------------------------- launch
extern "C" void kernel_launch(void* const* d_in, const int* in_sizes, int n_in,
                              void* d_out, int out_size, void* d_ws, size_t ws_size,
                              hipStream_t stream) {
    const int*   A_cols     = (const int*)d_in[1];
    const float* A_vals     = (const float*)d_in[2];
    const float* X          = (const float*)d_in[3];
    const float* W_gcn      = (const float*)d_in[4];
    const float* W_ih       = (const float*)d_in[5];
    const float* W_hh       = (const float*)d_in[6];
    const float* b_ih       = (const float*)d_in[7];
    const float* b_hh       = (const float*)d_in[8];
    const float* in_proj_w  = (const float*)d_in[9];
    const float* in_proj_b  = (const float*)d_in[10];
    const float* out_proj_w = (const float*)d_in[11];
    const float* out_proj_b = (const float*)d_in[12];
    const float* ln1_g = (const float*)d_in[13];
    const float* ln1_b = (const float*)d_in[14];
    const float* ln2_g = (const float*)d_in[15];
    const float* ln2_b = (const float*)d_in[16];
    const float* lnf_g = (const float*)d_in[17];
    const float* lnf_b = (const float*)d_in[18];
    const float* ff1_w = (const float*)d_in[19];
    const float* ff1_b = (const float*)d_in[20];
    const float* ff2_w = (const float*)d_in[21];
    const float* ff2_b = (const float*)d_in[22];
    const float* fc1_w = (const float*)d_in[23];
    const float* fc1_b = (const float*)d_in[24];
    const float* fc2_w = (const float*)d_in[25];
    const float* fc2_b = (const float*)d_in[26];
    const float* fc3_w = (const float*)d_in[27];
    const float* fc3_b = (const float*)d_in[28];
    float* out = (float*)d_out;
    float* ws  = (float*)d_ws;

    const size_t o_Hm = 0;
    const size_t o_A  = o_Hm + 4194304;
    const size_t o_B  = o_A + 4194304;
    const size_t o_C  = o_B + 4194304;           // GI -> ff_hid(bf16)
    const size_t o_D  = o_C + 12582912;          // Qb/Kb/VTb/Vb bf16 -> head partials
    const size_t o_WT = o_D + 12582912;          // bf16 weights (scan)
    const size_t o_h  = o_WT + 49152;
    const size_t o_g  = o_h + 131072;
    const size_t o_h1 = o_g + 131072;
    const size_t o_h2 = o_h1 + 524288;

    float* Hm    = ws + o_Hm;
    float* bufA  = ws + o_A;
    short* Xs    = (short*)bufA;                 // X_s bf16 [N, TF] (dead after step 2)
    float* bufB  = ws + o_B;
    float* bufC  = ws + o_C;
    short* ffh   = (short*)bufC;                 // ff_hid bf16 [NT, 512]
    short* Qb    = (short*)(ws + o_D);
    short* Kb    = Qb + 4194304;
    short* VTb   = Kb + 4194304;
    short* Vb    = VTb + 4194304;
    float* partbuf = ws + o_D;                   // head partials (o_D dead after attn)
    unsigned short* WhhT_bf = (unsigned short*)(ws + o_WT);   // 49152 ushort
    unsigned short* Wg_bf   = WhhT_bf + 49152;                // 16384 ushort
    float* g0    = ws + o_g;
    float* h1    = ws + o_h1;
    float* h2    = ws + o_h2;
    float* g1    = h2;                           // alias: h2 dead during scan

    // 1. X_s = A_hat @ X -> Xs (bf16); c-slice-major dispatch for L2 locality
    spmm_wide<<<dim3(1024, 16), 256, 0, stream>>>(A_cols, A_vals, X, Xs);
    // 2. X_tilde = relu(X_s @ W_gcn) -> bufB  (bf16 A)
    mfma_gemm<false, true, false, true><<<dim3(2, 512), 256, 0, stream>>>(Xs, W_gcn, nullptr, bufB, NT, F_DIM, F_DIM, 0);
    // 3. GI = X_tilde @ W_ih^T + b_ih -> bufC  (128-tile)
    mfma_gemm128<false, false, false><<<dim3(3, 256), 256, 0, stream>>>(bufB, W_ih, b_ih, bufC, NT, F_DIM, F3);
    // 4. bf16 weight prep (scan)
    prep_weights<<<192, 256, 0, stream>>>(W_hh, W_gcn, WhhT_bf, Wg_bf);
    // 5. g(0), Hm[:,0]  (h0=0, GH0=0 algebraically)
    gates0_kernel<<<512, 256, 0, stream>>>(bufC, b_hh, g0, Hm);
    // 6. fused scan: one launch per step; h/GH stay on-chip (512 blocks = 2/CU)
    for (int s = 0; s < T_STEPS - 1; ++s) {
        const float* gi = (s & 1) ? g1 : g0;
        float*       go = (s & 1) ? g0 : g1;
        scan_step<<<512, 256, 0, stream>>>(A_cols, A_vals, gi, Wg_bf, WhhT_bf, b_hh, bufC, go, Hm, s + 1);
    }
    // 7. qkv projection (128-tile) -> Qb/Kb/Vb (all K-layout)
    qkv_gemm128<<<dim3(3, 256), 256, 0, stream>>>(Hm, in_proj_w, in_proj_b, Qb, Kb, Vb);
    // 7b. V transpose through LDS (coalesced both sides)
    vtrans<<<dim3(128, 32), 256, 0, stream>>>(Vb, VTb);
    // 8. MFMA attention -> ctx (bufA)
    attn_mfma<<<dim3(128, 16), 256, 0, stream>>>(Qb, Kb, VTb, bufA);
    // 9. attn_out = ctx @ out_proj_w^T + b -> bufB
    mfma_gemm<true, false, false, false><<<dim3(2, 512), 256, 0, stream>>>(bufA, out_proj_w, out_proj_b, bufB, NT, F_DIM, F_DIM, 0);
    // 10. x1 = LN(Hm + attn_out) -> bufA
    ln_kernel<<<NT / 4, 256, 0, stream>>>(Hm, bufB, ln1_g, ln1_b, bufA);
    // 11. ff_hid = relu(x1 @ ff1_w^T + b) -> ffh (bf16, 128-tile)
    mfma_gemm128<true, false, true><<<dim3(4, 256), 256, 0, stream>>>(bufA, ff1_w, ff1_b, ffh, NT, F_DIM, HID);
    // 12. ff_out = ff_hid @ ff2_w^T + b -> bufB  (64-tile, bf16 A, 1024 blocks)
    mfma_gemm<true, false, false, true><<<dim3(2, 512), 256, 0, stream>>>(ffh, ff2_w, ff2_b, bufB, NT, HID, F_DIM, 0);
    // 13+14. enc = LN(LN(x1 + ff_out)) -> bufA  (fused)
    ln2_lnf_kernel<<<NT / 4, 256, 0, stream>>>(bufA, bufB, ln2_g, ln2_b, lnf_g, lnf_b, bufA);
    // 15. h1 = relu(enc_flat @ fc1_w^T + b)  — split-K=4 partials + reduce
    mfma_gemm<true, false, true, false><<<dim3(8, 16, 4), 256, 0, stream>>>(bufA, fc1_w, nullptr, partbuf, N_NODES, TF, HID, 1024);
    reduce_bias<true><<<2048, 256, 0, stream>>>(partbuf, 4, 524288, fc1_b, HID, h1);
    // 16. h2 = relu(h1 @ fc2_w^T + b) — split-K=4 partials + reduce
    mfma_gemm<true, false, true, false><<<dim3(8, 16, 4), 256, 0, stream>>>(h1, fc2_w, nullptr, partbuf, N_NODES, HID, HID, 128);
    reduce_bias<true><<<2048, 256, 0, stream>>>(partbuf, 4, 524288, fc2_b, HID, h2);
    // 17. out = h2 @ fc3_w^T + b — split-K=8 partials + reduce
    mfma_gemm<true, false, true, false><<<dim3(1, 16, 8), 256, 0, stream>>>(h2, fc3_w, nullptr, partbuf, N_NODES, HID, OUT_DIM, 64);
    reduce_bias<false><<<256, 256, 0, stream>>>(partbuf, 8, 65536, fc3_b, OUT_DIM, out);
}

// Round 16
// 719.965 us; speedup vs baseline: 1.1882x; 1.0084x over previous
//
#include <hip/hip_runtime.h>
#include <hip/hip_bf16.h>
#include <math.h>

#define N_NODES 1024
#define T_STEPS 32
#define F_DIM   128
#define H_HEADS 4
#define D_HEAD  32
#define DEG     32
#define HID     512
#define OUT_DIM 64
#define TF      (T_STEPS * F_DIM)   // 4096
#define NT      (N_NODES * T_STEPS) // 32768
#define F3      (3 * F_DIM)         // 384

typedef __attribute__((ext_vector_type(8))) __bf16 bf16x8;
typedef __attribute__((ext_vector_type(4))) float  f32x4;

// float -> bf16 bits, round-to-nearest-even (scalar fallback)
__device__ __forceinline__ short f2bf(float x) {
    union { float f; unsigned u; } v; v.f = x;
    unsigned r = (v.u + 0x7FFFu + ((v.u >> 16) & 1u)) >> 16;
    return (short)r;
}
__device__ __forceinline__ float bf2f(unsigned short b) {
    union { unsigned u; float f; } v; v.u = ((unsigned)b) << 16; return v.f;
}

// ---------------------------------------------------------------- utilities
// one-time: W_hh [384,128] -> bf16 WhhT [128,384]; W_gcn [128,128] -> bf16 (same layout)
__global__ void prep_weights(const float* __restrict__ W_hh, const float* __restrict__ W_gcn,
                             unsigned short* __restrict__ WhhT_bf,
                             unsigned short* __restrict__ Wg_bf) {
    int idx = blockIdx.x * 256 + threadIdx.x;
    if (idx < F3 * F_DIM) {
        int j = idx / F_DIM;   // 0..383
        int k = idx % F_DIM;   // 0..127
        WhhT_bf[k * F3 + j] = (unsigned short)f2bf(W_hh[idx]);
    }
    if (idx < F_DIM * F_DIM) {
        Wg_bf[idx] = (unsigned short)f2bf(W_gcn[idx]);
    }
}

// split-K partial reduction + bias (+relu)
template <bool RELU>
__global__ void reduce_bias(const float* __restrict__ part, int nz, int MP,
                            const float* __restrict__ bias, int P,
                            float* __restrict__ C) {
    int i = blockIdx.x * 256 + threadIdx.x;
    if (i < MP) {
        float v = bias[i & (P - 1)];
        for (int z = 0; z < nz; ++z) v += part[(size_t)z * MP + i];
        if (RELU) v = fmaxf(v, 0.f);
        C[i] = v;
    }
}

// ---------------------------------------------------------------- SpMM (wide): Y[n, :] = sum_e vals * X[cols[e], :]
__global__ void spmm_wide(const int* __restrict__ cols, const float* __restrict__ vals,
                          const float* __restrict__ X, short* __restrict__ Y) {
    int n = blockIdx.x;
    int c = blockIdx.y * 256 + threadIdx.x;
    const int*   ce = cols + n * DEG;
    const float* ve = vals + n * DEG;
    float acc = 0.f;
#pragma unroll
    for (int e = 0; e < DEG; ++e) acc += ve[e] * X[(size_t)ce[e] * TF + c];
    Y[(size_t)n * TF + c] = f2bf(acc);
}

// ---------------------------------------------------------------- t=0 gates: h=0, GH=0 algebraically; pe(t=0)=sin(0)=0
__global__ __launch_bounds__(256) void gates0_kernel(
        const float* __restrict__ GI, const float* __restrict__ b_hh,
        float* __restrict__ g_out, float* __restrict__ Hm) {
    int idx = blockIdx.x * 256 + threadIdx.x;   // over N*F
    int n = idx >> 7, f = idx & 127;
    size_t gib = (size_t)n * T_STEPS * F3;
    float rr = 1.f / (1.f + expf(-(GI[gib + f] + b_hh[f])));
    float zz = 1.f / (1.f + expf(-(GI[gib + 128 + f] + b_hh[128 + f])));
    float nn = tanhf(GI[gib + 256 + f] + rr * b_hh[256 + f]);
    float g  = (1.f - zz) * nn;
    g_out[idx] = g;
    Hm[(size_t)n * T_STEPS * F_DIM + f] = g;    // pe = 0 at t=0
}

// ---------------------------------------------------------------- fully fused scan step, 2 nodes/block (512 blocks)
// Weight reads are scalar-per-thread but wave-coalesced (64 lanes x 2B = one line).
__global__ __launch_bounds__(256) void scan_step(
        const int* __restrict__ cols, const float* __restrict__ vals,
        const float* __restrict__ g_in, const unsigned short* __restrict__ Wg_bf,
        const unsigned short* __restrict__ WhhT_bf, const float* __restrict__ b_hh,
        const float* __restrict__ GI, float* __restrict__ g_out,
        float* __restrict__ Hm, int t_next) {
    __shared__ float sp[2][F_DIM];
    __shared__ float hsn[2][F_DIM];
    __shared__ float part[2][F_DIM][8];    // 6 used, +2 pad
    __shared__ float gpart[2][2][F_DIM];
    int tid = threadIdx.x;
    int n0 = blockIdx.x * 2;
    int f = tid & 127, half = tid >> 7;
    // ---- SpMM: edges split across halves
    float b0 = 0.f, b1 = 0.f;
    int eb = half * 16;
#pragma unroll
    for (int e = 0; e < 16; ++e) {
        int i0 = n0 * DEG + eb + e;
        int i1 = (n0 + 1) * DEG + eb + e;
        b0 += vals[i0] * g_in[cols[i0] * F_DIM + f];
        b1 += vals[i1] * g_in[cols[i1] * F_DIM + f];
    }
    gpart[half][0][f] = b0; gpart[half][1][f] = b1;
    __syncthreads();
    sp[half][f] = gpart[0][half][f] + gpart[1][half][f];   // half doubles as node idx
    __syncthreads();
    // ---- GCN: k range split across halves (bf16 weights, coalesced)
    float c0 = 0.f, c1 = 0.f;
    int kb = half * 64;
#pragma unroll 4
    for (int k = 0; k < 64; ++k) {
        int kk = kb + k;
        float w = bf2f(Wg_bf[kk * F_DIM + f]);
        c0 += sp[0][kk] * w; c1 += sp[1][kk] * w;
    }
    gpart[half][0][f] = c0; gpart[half][1][f] = c1;
    __syncthreads();
    hsn[half][f] = fmaxf(gpart[0][half][f] + gpart[1][half][f], 0.f);
    __syncthreads();
    // ---- GH = h_new @ W_hh^T : k split, 2 nodes x 3 gates (bf16 weights, coalesced)
    float a[6] = {0.f, 0.f, 0.f, 0.f, 0.f, 0.f};
#pragma unroll 2
    for (int k = 0; k < 64; ++k) {
        int kk = kb + k;
        const unsigned short* w = WhhT_bf + kk * F3;
        float wr = bf2f(w[f]), wz = bf2f(w[128 + f]), wn = bf2f(w[256 + f]);
        float h0 = hsn[0][kk], h1 = hsn[1][kk];
        a[0] += h0 * wr; a[1] += h0 * wz; a[2] += h0 * wn;
        a[3] += h1 * wr; a[4] += h1 * wz; a[5] += h1 * wn;
    }
#pragma unroll
    for (int i = 0; i < 6; ++i) part[half][f][i] = a[i];
    __syncthreads();
    // ---- gates for own node (node = n0+half), all inputs local
    {
        int node = n0 + half;
        float ghr = part[0][f][half * 3 + 0] + part[1][f][half * 3 + 0] + b_hh[f];
        float ghz = part[0][f][half * 3 + 1] + part[1][f][half * 3 + 1] + b_hh[128 + f];
        float ghn = part[0][f][half * 3 + 2] + part[1][f][half * 3 + 2] + b_hh[256 + f];
        size_t gib = ((size_t)node * T_STEPS + t_next) * F3;
        float hv = hsn[half][f];
        float rr = 1.f / (1.f + expf(-(GI[gib + f] + ghr)));
        float zz = 1.f / (1.f + expf(-(GI[gib + 128 + f] + ghz)));
        float nn = tanhf(GI[gib + 256 + f] + rr * ghn);
        float g  = (1.f - zz) * nn + zz * hv;
        g_out[node * F_DIM + f] = g;
        float inv = __expf(-(float)node * (9.210340371976184f / 64.0f));
        float ang = (float)t_next * inv;
        float pe  = ((t_next & 1) == 0) ? sinf(ang) : cosf(ang);
        Hm[((size_t)node * T_STEPS + t_next) * F_DIM + f] = g + pe;
    }
}

// ================================================================ 128x128-tile bf16 MFMA GEMM core (B is [P,K])
template <bool RELU, bool ABF16, bool BF16OUT>
__global__ __launch_bounds__(256) void mfma_gemm128(const void* __restrict__ Aptr,
                                                    const float* __restrict__ B,
                                                    const float* __restrict__ bias,
                                                    void* __restrict__ Cptr,
                                                    int M, int K, int P) {
    __shared__ short As[128][40];
    __shared__ short Bs[128][40];
    int tid = threadIdx.x;
    int p0 = blockIdx.x * 128, row0 = blockIdx.y * 128;
    int lane = tid & 63, w = tid >> 6, col = lane & 15, quad = lane >> 4;
    int qr = w >> 1, qc = w & 1;
    f32x4 acc[4][4];
#pragma unroll
    for (int j = 0; j < 4; ++j)
#pragma unroll
        for (int jj = 0; jj < 4; ++jj) acc[j][jj] = (f32x4){0.f, 0.f, 0.f, 0.f};

    for (int k0 = 0; k0 < K; k0 += 32) {
        if (ABF16) {
            const short* A = (const short*)Aptr;
#pragma unroll
            for (int i = 0; i < 2; ++i) {
                int idx = tid * 2 + i;              // 512 chunks of 8 shorts
                int r = idx >> 2, c8 = (idx & 3) * 8;
                *(int4*)&As[r][c8] = *(const int4*)(A + (size_t)(row0 + r) * K + k0 + c8);
            }
        } else {
            const float* A = (const float*)Aptr;
#pragma unroll
            for (int i = 0; i < 4; ++i) {
                int idx = tid * 4 + i;
                int r = idx >> 3, c4 = (idx & 7) << 2;
                const float4 f4 = *(const float4*)(A + (size_t)(row0 + r) * K + k0 + c4);
                union { __hip_bfloat162 h2[2]; short4 s4; } u;
                u.h2[0] = __float22bfloat162_rn(make_float2(f4.x, f4.y));
                u.h2[1] = __float22bfloat162_rn(make_float2(f4.z, f4.w));
                *(short4*)&As[r][c4] = u.s4;
            }
        }
#pragma unroll
        for (int i = 0; i < 4; ++i) {
            int idx = tid * 4 + i;
            int r = idx >> 3, c4 = (idx & 7) << 2;
            const float4 f4 = *(const float4*)(B + (size_t)(p0 + r) * K + k0 + c4);
            union { __hip_bfloat162 h2[2]; short4 s4; } u;
            u.h2[0] = __float22bfloat162_rn(make_float2(f4.x, f4.y));
            u.h2[1] = __float22bfloat162_rn(make_float2(f4.z, f4.w));
            *(short4*)&Bs[r][c4] = u.s4;
        }
        __syncthreads();
        bf16x8 af[4], bfr[4];
#pragma unroll
        for (int j = 0; j < 4; ++j) af[j]  = *(const bf16x8*)&As[qr * 64 + j * 16 + col][quad * 8];
#pragma unroll
        for (int j = 0; j < 4; ++j) bfr[j] = *(const bf16x8*)&Bs[qc * 64 + j * 16 + col][quad * 8];
#pragma unroll
        for (int j = 0; j < 4; ++j)
#pragma unroll
            for (int jj = 0; jj < 4; ++jj)
                acc[j][jj] = __builtin_amdgcn_mfma_f32_16x16x32_bf16(af[j], bfr[jj], acc[j][jj], 0, 0, 0);
        __syncthreads();
    }
#pragma unroll
    for (int j = 0; j < 4; ++j) {
#pragma unroll
        for (int jj = 0; jj < 4; ++jj) {
            int cg = p0 + qc * 64 + jj * 16 + col;
            float bvv = bias ? bias[cg] : 0.f;
#pragma unroll
            for (int r = 0; r < 4; ++r) {
                int rg = row0 + qr * 64 + j * 16 + quad * 4 + r;
                float v = acc[j][jj][r] + bvv;
                if (RELU) v = fmaxf(v, 0.f);
                if (BF16OUT) ((short*)Cptr)[(size_t)rg * P + cg] = f2bf(v);
                else         ((float*)Cptr)[(size_t)rg * P + cg] = v;
            }
        }
    }
}

// qkv variant: same 128x128 core, epilogue writes bf16 Qb/Kb/Vb all in [T*H,N,D]
// Q scaled by 1/sqrt(D) * log2(e) so attention can use exp2 directly.
__global__ __launch_bounds__(256) void qkv_gemm128(const float* __restrict__ A,
                                                   const float* __restrict__ B,
                                                   const float* __restrict__ bias,
                                                   short* __restrict__ Qb,
                                                   short* __restrict__ Kb,
                                                   short* __restrict__ Vb) {
    __shared__ short As[128][40];
    __shared__ short Bs[128][40];
    int tid = threadIdx.x;
    int p0 = blockIdx.x * 128, row0 = blockIdx.y * 128;
    int lane = tid & 63, w = tid >> 6, col = lane & 15, quad = lane >> 4;
    int qr = w >> 1, qc = w & 1;
    const int K = F_DIM;
    f32x4 acc[4][4];
#pragma unroll
    for (int j = 0; j < 4; ++j)
#pragma unroll
        for (int jj = 0; jj < 4; ++jj) acc[j][jj] = (f32x4){0.f, 0.f, 0.f, 0.f};

    for (int k0 = 0; k0 < K; k0 += 32) {
#pragma unroll
        for (int i = 0; i < 4; ++i) {
            int idx = tid * 4 + i;
            int r = idx >> 3, c4 = (idx & 7) << 2;
            const float4 f4 = *(const float4*)(A + (size_t)(row0 + r) * K + k0 + c4);
            union { __hip_bfloat162 h2[2]; short4 s4; } u;
            u.h2[0] = __float22bfloat162_rn(make_float2(f4.x, f4.y));
            u.h2[1] = __float22bfloat162_rn(make_float2(f4.z, f4.w));
            *(short4*)&As[r][c4] = u.s4;
        }
#pragma unroll
        for (int i = 0; i < 4; ++i) {
            int idx = tid * 4 + i;
            int r = idx >> 3, c4 = (idx & 7) << 2;
            const float4 f4 = *(const float4*)(B + (size_t)(p0 + r) * K + k0 + c4);
            union { __hip_bfloat162 h2[2]; short4 s4; } u;
            u.h2[0] = __float22bfloat162_rn(make_float2(f4.x, f4.y));
            u.h2[1] = __float22bfloat162_rn(make_float2(f4.z, f4.w));
            *(short4*)&Bs[r][c4] = u.s4;
        }
        __syncthreads();
        bf16x8 af[4], bfr[4];
#pragma unroll
        for (int j = 0; j < 4; ++j) af[j]  = *(const bf16x8*)&As[qr * 64 + j * 16 + col][quad * 8];
#pragma unroll
        for (int j = 0; j < 4; ++j) bfr[j] = *(const bf16x8*)&Bs[qc * 64 + j * 16 + col][quad * 8];
#pragma unroll
        for (int j = 0; j < 4; ++j)
#pragma unroll
            for (int jj = 0; jj < 4; ++jj)
                acc[j][jj] = __builtin_amdgcn_mfma_f32_16x16x32_bf16(af[j], bfr[jj], acc[j][jj], 0, 0, 0);
        __syncthreads();
    }
#pragma unroll
    for (int j = 0; j < 4; ++j) {
#pragma unroll
        for (int jj = 0; jj < 4; ++jj) {
            int cg = p0 + qc * 64 + jj * 16 + col;
            int which = cg >> 7, f = cg & 127;
            int hh = f >> 5, d = f & 31;
            float bv = bias[cg];
#pragma unroll
            for (int r = 0; r < 4; ++r) {
                int rg = row0 + qr * 64 + j * 16 + quad * 4 + r;
                int n = rg >> 5, t = rg & 31;
                int th = t * H_HEADS + hh;
                size_t dst = ((size_t)th * N_NODES + n) * D_HEAD + d;
                float v = acc[j][jj][r] + bv;
                if (which == 0)      Qb[dst] = f2bf(v * (0.17677669529663687f * 1.4426950408889634f));
                else if (which == 1) Kb[dst] = f2bf(v);
                else                 Vb[dst] = f2bf(v);
            }
        }
    }
}

// ---------------------------------------------------------------- V transpose: Vb [T*H,N,D] -> VTb [T*H,D,N], coalesced
__global__ __launch_bounds__(256) void vtrans(const short* __restrict__ Vb,
                                              short* __restrict__ VTb) {
    __shared__ short tile[32][36];
    int th = blockIdx.x;
    int n0 = blockIdx.y * 32;
    int tid = threadIdx.x;
    {
        int n_i = tid >> 3, d0 = (tid & 7) * 4;
        *(short4*)&tile[n_i][d0] =
            *(const short4*)(Vb + ((size_t)th * N_NODES + n0 + n_i) * D_HEAD + d0);
    }
    __syncthreads();
    {
        int d = tid >> 3, m0 = (tid & 7) * 4;
        short4 o;
        o.x = tile[m0 + 0][d]; o.y = tile[m0 + 1][d];
        o.z = tile[m0 + 2][d]; o.w = tile[m0 + 3][d];
        *(short4*)(VTb + ((size_t)th * D_HEAD + d) * N_NODES + n0 + m0) = o;
    }
}

// ---------------------------------------------------------------- MFMA flash attention, 4 waves/block sharing K/V via LDS
// Q pre-scaled by log2(e): weights are exp2(s) via v_exp_f32. ctx written bf16
// (bit-identical: consumer GEMM rounds A to bf16 in staging anyway).
__global__ __launch_bounds__(256) void attn_mfma(const short* __restrict__ Qb,
                                                 const short* __restrict__ Kb,
                                                 const short* __restrict__ VTb,
                                                 short* __restrict__ ctx) {
    int th = blockIdx.x;
    int t = th >> 2, hh = th & 3;
    int q0 = blockIdx.y * 64;
    int tid = threadIdx.x;
    int w = tid >> 6, lane = tid & 63;
    int col = lane & 15, quad = lane >> 4;
    __shared__ short    Ks[32][40];       // row stride 80B (16B-aligned)
    __shared__ short    Vs[32][40];
    __shared__ unsigned Ps[4][16][20];    // dwords; row stride 80B

    bf16x8 qf = *(const bf16x8*)(Qb + ((size_t)th * N_NODES + q0 + w * 16 + col) * D_HEAD + quad * 8);
    const short* Kbase = Kb  + (size_t)th * (N_NODES * D_HEAD);
    const short* Vbase = VTb + (size_t)th * (D_HEAD * N_NODES);

    int lrw = tid >> 3;                    // staging row 0..31
    int lc  = (tid & 7) * 4;               // staging col (shorts)
    int kperm = ((lrw & 15) << 1) | (lrw >> 4);   // rows 0..15 -> even m, 16..31 -> odd m

    f32x4 o0 = {0.f, 0.f, 0.f, 0.f}, o1 = {0.f, 0.f, 0.f, 0.f};
    float l0 = 0.f, l1 = 0.f, l2 = 0.f, l3 = 0.f;
    const f32x4 zc = {0.f, 0.f, 0.f, 0.f};

    for (int mt = 0; mt < 32; ++mt) {
        int m0 = mt * 32;
        __syncthreads();   // WAR: previous iteration's Ks/Vs reads done
        *(short4*)&Ks[lrw][lc] = *(const short4*)(Kbase + (size_t)(m0 + kperm) * D_HEAD + lc);
        *(short4*)&Vs[lrw][lc] = *(const short4*)(Vbase + (size_t)lrw * N_NODES + m0 + lc);
        __syncthreads();   // tiles visible
        bf16x8 k0 = *(const bf16x8*)&Ks[col][quad * 8];        // K[m0+2col]
        bf16x8 k1 = *(const bf16x8*)&Ks[col + 16][quad * 8];   // K[m0+2col+1]
        f32x4 s0 = __builtin_amdgcn_mfma_f32_16x16x32_bf16(qf, k0, zc, 0, 0, 0);
        f32x4 s1 = __builtin_amdgcn_mfma_f32_16x16x32_bf16(qf, k1, zc, 0, 0, 0);
        float ps[4][2];
#pragma unroll
        for (int r = 0; r < 4; ++r) {
            ps[r][0] = __builtin_amdgcn_exp2f(s0[r]);
            ps[r][1] = __builtin_amdgcn_exp2f(s1[r]);
            union { __hip_bfloat162 h; unsigned u; } u;
            u.h = __float22bfloat162_rn(make_float2(ps[r][0], ps[r][1]));
            Ps[w][quad * 4 + r][col] = u.u;   // natural m order
        }
        l0 += ps[0][0] + ps[0][1]; l1 += ps[1][0] + ps[1][1];
        l2 += ps[2][0] + ps[2][1]; l3 += ps[3][0] + ps[3][1];
        __builtin_amdgcn_s_waitcnt(0xC07F);   // lgkmcnt(0): own Ps writes committed
        bf16x8 pf = *(const bf16x8*)&Ps[w][col][quad * 4];     // A-frag, natural m order
        bf16x8 v0 = *(const bf16x8*)&Vs[col][quad * 8];        // V^T[d=col][m0+quad*8..]
        bf16x8 v1 = *(const bf16x8*)&Vs[col + 16][quad * 8];
        o0 = __builtin_amdgcn_mfma_f32_16x16x32_bf16(pf, v0, o0, 0, 0, 0);
        o1 = __builtin_amdgcn_mfma_f32_16x16x32_bf16(pf, v1, o1, 0, 0, 0);
    }
    float lr[4] = {l0, l1, l2, l3};
#pragma unroll
    for (int r = 0; r < 4; ++r) {
        float s = lr[r];
        s += __shfl_xor(s, 1); s += __shfl_xor(s, 2);
        s += __shfl_xor(s, 4); s += __shfl_xor(s, 8);
        lr[r] = 1.f / s;
    }
#pragma unroll
    for (int r = 0; r < 4; ++r) {
        int n = q0 + w * 16 + quad * 4 + r;
        size_t base = ((size_t)n * T_STEPS + t) * F_DIM + hh * D_HEAD;
        ctx[base + col]      = f2bf(o0[r] * lr[r]);
        ctx[base + 16 + col] = f2bf(o1[r] * lr[r]);
    }
}

// ---------------------------------------------------------------- LayerNorm over F=128, 4 rows/block, optional residual
__global__ __launch_bounds__(256) void ln_kernel(
        const float* __restrict__ a, const float* __restrict__ resid,
        const float* __restrict__ gamma, const float* __restrict__ beta,
        float* __restrict__ out) {
    int row = blockIdx.x * 4 + (threadIdx.x >> 6);
    int tid = threadIdx.x & 63;
    int base = row * F_DIM;
    float x0 = a[base + tid], x1 = a[base + 64 + tid];
    if (resid) { x0 += resid[base + tid]; x1 += resid[base + 64 + tid]; }
    float s = x0 + x1;
#pragma unroll
    for (int o = 32; o > 0; o >>= 1) s += __shfl_xor(s, o);
    float mu = s * (1.f / 128.f);
    float d0 = x0 - mu, d1 = x1 - mu;
    float v = d0 * d0 + d1 * d1;
#pragma unroll
    for (int o = 32; o > 0; o >>= 1) v += __shfl_xor(v, o);
    float inv = rsqrtf(v * (1.f / 128.f) + 1e-5f);
    out[base + tid]      = d0 * inv * gamma[tid] + beta[tid];
    out[base + 64 + tid] = d1 * inv * gamma[64 + tid] + beta[64 + tid];
}

// fused LN2 + LNF: enc = LN(LN(a+resid; g2,b2); gf,bf) — x2 never materialized
__global__ __launch_bounds__(256) void ln2_lnf_kernel(
        const float* __restrict__ a, const float* __restrict__ resid,
        const float* __restrict__ g2, const float* __restrict__ b2,
        const float* __restrict__ gf, const float* __restrict__ bfp,
        float* __restrict__ out) {
    int row = blockIdx.x * 4 + (threadIdx.x >> 6);
    int tid = threadIdx.x & 63;
    int base = row * F_DIM;
    float x0 = a[base + tid] + resid[base + tid];
    float x1 = a[base + 64 + tid] + resid[base + 64 + tid];
    float s = x0 + x1;
#pragma unroll
    for (int o = 32; o > 0; o >>= 1) s += __shfl_xor(s, o);
    float mu = s * (1.f / 128.f);
    float d0 = x0 - mu, d1 = x1 - mu;
    float v = d0 * d0 + d1 * d1;
#pragma unroll
    for (int o = 32; o > 0; o >>= 1) v += __shfl_xor(v, o);
    float inv = rsqrtf(v * (1.f / 128.f) + 1e-5f);
    float y0 = d0 * inv * g2[tid] + b2[tid];
    float y1 = d1 * inv * g2[64 + tid] + b2[64 + tid];
    s = y0 + y1;
#pragma unroll
    for (int o = 32; o > 0; o >>= 1) s += __shfl_xor(s, o);
    mu = s * (1.f / 128.f);
    d0 = y0 - mu; d1 = y1 - mu;
    v = d0 * d0 + d1 * d1;
#pragma unroll
    for (int o = 32; o > 0; o >>= 1) v += __shfl_xor(v, o);
    inv = rsqrtf(v * (1.f / 128.f) + 1e-5f);
    out[base + tid]      = d0 * inv * gf[tid] + bfp[tid];
    out[base + 64 + tid] = d1 * inv * gf[64 + tid] + bfp[64 + tid];
}

// ---------------------------------------------------------------- 64x64 bf16 MFMA GEMM
template <bool TB, bool RELU, bool SPLITK, bool ABF16, bool BF16OUT>
__global__ __launch_bounds__(256) void mfma_gemm(const void* __restrict__ Aptr,
                                                 const float* __restrict__ B,
                                                 const float* __restrict__ bias,
                                                 void* __restrict__ Cptr,
                                                 int M, int K, int P, int Kc) {
    __shared__ short As[64][40];
    __shared__ short Bs[64][40];
    int tid = threadIdx.x;
    int p0 = blockIdx.x * 64, row0 = blockIdx.y * 64;
    int k_begin = SPLITK ? blockIdx.z * Kc : 0;
    int k_end   = SPLITK ? k_begin + Kc : K;
    int lane = tid & 63, w = tid >> 6, col = lane & 15, quad = lane >> 4;
    f32x4 acc[4];
#pragma unroll
    for (int j = 0; j < 4; ++j) acc[j] = (f32x4){0.f, 0.f, 0.f, 0.f};

    for (int k0 = k_begin; k0 < k_end; k0 += 32) {
        if (ABF16) {
            const short* A = (const short*)Aptr;
            int r = tid >> 2, c8 = (tid & 3) * 8;
            *(int4*)&As[r][c8] = *(const int4*)(A + (size_t)(row0 + r) * K + k0 + c8);
        } else {
            const float* A = (const float*)Aptr;
#pragma unroll
            for (int i = 0; i < 2; ++i) {
                int idx = tid * 2 + i;
                int r = idx >> 3, c4 = (idx & 7) << 2;
                const float4 f4 = *(const float4*)(A + (size_t)(row0 + r) * K + k0 + c4);
                union { __hip_bfloat162 h2[2]; short4 s4; } u;
                u.h2[0] = __float22bfloat162_rn(make_float2(f4.x, f4.y));
                u.h2[1] = __float22bfloat162_rn(make_float2(f4.z, f4.w));
                *(short4*)&As[r][c4] = u.s4;
            }
        }
        if (TB) {
#pragma unroll
            for (int i = 0; i < 2; ++i) {
                int idx = tid * 2 + i;
                int r = idx >> 3, c4 = (idx & 7) << 2;
                const float4 f4 = *(const float4*)(B + (size_t)(p0 + r) * K + k0 + c4);
                union { __hip_bfloat162 h2[2]; short4 s4; } u;
                u.h2[0] = __float22bfloat162_rn(make_float2(f4.x, f4.y));
                u.h2[1] = __float22bfloat162_rn(make_float2(f4.z, f4.w));
                *(short4*)&Bs[r][c4] = u.s4;
            }
        } else {
#pragma unroll
            for (int i = 0; i < 2; ++i) {
                int idx = tid * 2 + i;
                int kk = idx >> 4, c4 = (idx & 15) << 2;
                const float4 f4 = *(const float4*)(B + (size_t)(k0 + kk) * P + p0 + c4);
                Bs[c4 + 0][kk] = f2bf(f4.x);
                Bs[c4 + 1][kk] = f2bf(f4.y);
                Bs[c4 + 2][kk] = f2bf(f4.z);
                Bs[c4 + 3][kk] = f2bf(f4.w);
            }
        }
        __syncthreads();
        bf16x8 af = *(const bf16x8*)&As[w * 16 + col][quad * 8];
#pragma unroll
        for (int j = 0; j < 4; ++j) {
            bf16x8 bv = *(const bf16x8*)&Bs[j * 16 + col][quad * 8];
            acc[j] = __builtin_amdgcn_mfma_f32_16x16x32_bf16(af, bv, acc[j], 0, 0, 0);
        }
        __syncthreads();
    }
    size_t zoff = SPLITK ? (size_t)blockIdx.z * M * P : 0;
#pragma unroll
    for (int j = 0; j < 4; ++j) {
        int cg_ = p0 + j * 16 + col;
        float bvv = (!SPLITK && bias) ? bias[cg_] : 0.f;
#pragma unroll
        for (int r = 0; r < 4; ++r) {
            int rg = row0 + w * 16 + quad * 4 + r;
            float v = acc[j][r] + bvv;
            if (!SPLITK && RELU) v = fmaxf(v, 0.f);
            if (BF16OUT) ((short*)Cptr)[(size_t)rg * P + cg_] = f2bf(v);
            else         ((float*)Cptr)[zoff + (size_t)rg * P + cg_] = v;
        }
    }
}

// ---------------------------------------------------------------- launch
extern "C" void kernel_launch(void* const* d_in, const int* in_sizes, int n_in,
                              void* d_out, int out_size, void* d_ws, size_t ws_size,
                              hipStream_t stream) {
    const int*   A_cols     = (const int*)d_in[1];
    const float* A_vals     = (const float*)d_in[2];
    const float* X          = (const float*)d_in[3];
    const float* W_gcn      = (const float*)d_in[4];
    const float* W_ih       = (const float*)d_in[5];
    const float* W_hh       = (const float*)d_in[6];
    const float* b_ih       = (const float*)d_in[7];
    const float* b_hh       = (const float*)d_in[8];
    const float* in_proj_w  = (const float*)d_in[9];
    const float* in_proj_b  = (const float*)d_in[10];
    const float* out_proj_w = (const float*)d_in[11];
    const float* out_proj_b = (const float*)d_in[12];
    const float* ln1_g = (const float*)d_in[13];
    const float* ln1_b = (const float*)d_in[14];
    const float* ln2_g = (const float*)d_in[15];
    const float* ln2_b = (const float*)d_in[16];
    const float* lnf_g = (const float*)d_in[17];
    const float* lnf_b = (const float*)d_in[18];
    const float* ff1_w = (const float*)d_in[19];
    const float* ff1_b = (const float*)d_in[20];
    const float* ff2_w = (const float*)d_in[21];
    const float* ff2_b = (const float*)d_in[22];
    const float* fc1_w = (const float*)d_in[23];
    const float* fc1_b = (const float*)d_in[24];
    const float* fc2_w = (const float*)d_in[25];
    const float* fc2_b = (const float*)d_in[26];
    const float* fc3_w = (const float*)d_in[27];
    const float* fc3_b = (const float*)d_in[28];
    float* out = (float*)d_out;
    float* ws  = (float*)d_ws;

    const size_t o_Hm = 0;
    const size_t o_A  = o_Hm + 4194304;
    const size_t o_B  = o_A + 4194304;
    const size_t o_C  = o_B + 4194304;           // GI -> ff_hid(bf16)
    const size_t o_D  = o_C + 12582912;          // Qb/Kb/VTb/Vb bf16 -> head partials
    const size_t o_WT = o_D + 12582912;          // bf16 weights (scan)
    const size_t o_h  = o_WT + 49152;
    const size_t o_g  = o_h + 131072;
    const size_t o_h1 = o_g + 131072;
    const size_t o_h2 = o_h1 + 524288;

    float* Hm    = ws + o_Hm;
    float* bufA  = ws + o_A;
    short* Xs    = (short*)bufA;                 // X_s bf16 [N, TF] (dead after step 2)
    short* ctxb  = (short*)bufA;                 // ctx bf16 [NT, F] (attn out; dead after step 9)
    float* bufB  = ws + o_B;
    short* Xt    = (short*)bufB;                 // X_tilde bf16 [NT, F] (dead after step 3)
    float* bufC  = ws + o_C;
    short* ffh   = (short*)bufC;                 // ff_hid bf16 [NT, 512]
    short* Qb    = (short*)(ws + o_D);
    short* Kb    = Qb + 4194304;
    short* VTb   = Kb + 4194304;
    short* Vb    = VTb + 4194304;
    float* partbuf = ws + o_D;                   // head partials (o_D dead after attn)
    unsigned short* WhhT_bf = (unsigned short*)(ws + o_WT);   // 49152 ushort
    unsigned short* Wg_bf   = WhhT_bf + 49152;                // 16384 ushort
    float* g0    = ws + o_g;
    float* h1    = ws + o_h1;
    float* h2    = ws + o_h2;
    float* g1    = h2;                           // alias: h2 dead during scan

    // 1. X_s = A_hat @ X -> Xs (bf16); c-slice-major dispatch for L2 locality
    spmm_wide<<<dim3(1024, 16), 256, 0, stream>>>(A_cols, A_vals, X, Xs);
    // 2. X_tilde = relu(X_s @ W_gcn) -> Xt (bf16; bit-identical for step 3)
    mfma_gemm<false, true, false, true, true><<<dim3(2, 512), 256, 0, stream>>>(Xs, W_gcn, nullptr, Xt, NT, F_DIM, F_DIM, 0);
    // 3. GI = X_tilde @ W_ih^T + b_ih -> bufC  (128-tile, bf16 A)
    mfma_gemm128<false, true, false><<<dim3(3, 256), 256, 0, stream>>>(Xt, W_ih, b_ih, bufC, NT, F_DIM, F3);
    // 4. bf16 weight prep (scan)
    prep_weights<<<192, 256, 0, stream>>>(W_hh, W_gcn, WhhT_bf, Wg_bf);
    // 5. g(0), Hm[:,0]  (h0=0, GH0=0 algebraically)
    gates0_kernel<<<512, 256, 0, stream>>>(bufC, b_hh, g0, Hm);
    // 6. fused scan: one launch per step; h/GH stay on-chip (512 blocks = 2/CU)
    for (int s = 0; s < T_STEPS - 1; ++s) {
        const float* gi = (s & 1) ? g1 : g0;
        float*       go = (s & 1) ? g0 : g1;
        scan_step<<<512, 256, 0, stream>>>(A_cols, A_vals, gi, Wg_bf, WhhT_bf, b_hh, bufC, go, Hm, s + 1);
    }
    // 7. qkv projection (128-tile) -> Qb/Kb/Vb (all K-layout)
    qkv_gemm128<<<dim3(3, 256), 256, 0, stream>>>(Hm, in_proj_w, in_proj_b, Qb, Kb, Vb);
    // 7b. V transpose through LDS (coalesced both sides)
    vtrans<<<dim3(128, 32), 256, 0, stream>>>(Vb, VTb);
    // 8. MFMA attention -> ctx bf16 (bufA)
    attn_mfma<<<dim3(128, 16), 256, 0, stream>>>(Qb, Kb, VTb, ctxb);
    // 9. attn_out = ctx @ out_proj_w^T + b -> bufB  (bf16 A; bit-identical)
    mfma_gemm<true, false, false, true, false><<<dim3(2, 512), 256, 0, stream>>>(ctxb, out_proj_w, out_proj_b, bufB, NT, F_DIM, F_DIM, 0);
    // 10. x1 = LN(Hm + attn_out) -> bufA
    ln_kernel<<<NT / 4, 256, 0, stream>>>(Hm, bufB, ln1_g, ln1_b, bufA);
    // 11. ff_hid = relu(x1 @ ff1_w^T + b) -> ffh (bf16, 128-tile)
    mfma_gemm128<true, false, true><<<dim3(4, 256), 256, 0, stream>>>(bufA, ff1_w, ff1_b, ffh, NT, F_DIM, HID);
    // 12. ff_out = ff_hid @ ff2_w^T + b -> bufB  (64-tile, bf16 A, 1024 blocks)
    mfma_gemm<true, false, false, true, false><<<dim3(2, 512), 256, 0, stream>>>(ffh, ff2_w, ff2_b, bufB, NT, HID, F_DIM, 0);
    // 13+14. enc = LN(LN(x1 + ff_out)) -> bufA  (fused)
    ln2_lnf_kernel<<<NT / 4, 256, 0, stream>>>(bufA, bufB, ln2_g, ln2_b, lnf_g, lnf_b, bufA);
    // 15. h1 = relu(enc_flat @ fc1_w^T + b)  — split-K=4 partials + reduce
    mfma_gemm<true, false, true, false, false><<<dim3(8, 16, 4), 256, 0, stream>>>(bufA, fc1_w, nullptr, partbuf, N_NODES, TF, HID, 1024);
    reduce_bias<true><<<2048, 256, 0, stream>>>(partbuf, 4, 524288, fc1_b, HID, h1);
    // 16. h2 = relu(h1 @ fc2_w^T + b) — split-K=4 partials + reduce
    mfma_gemm<true, false, true, false, false><<<dim3(8, 16, 4), 256, 0, stream>>>(h1, fc2_w, nullptr, partbuf, N_NODES, HID, HID, 128);
    reduce_bias<true><<<2048, 256, 0, stream>>>(partbuf, 4, 524288, fc2_b, HID, h2);
    // 17. out = h2 @ fc3_w^T + b — split-K=8 partials + reduce
    mfma_gemm<true, false, true, false, false><<<dim3(1, 16, 8), 256, 0, stream>>>(h2, fc3_w, nullptr, partbuf, N_NODES, HID, OUT_DIM, 64);
    reduce_bias<false><<<256, 256, 0, stream>>>(partbuf, 8, 65536, fc3_b, OUT_DIM, out);
}